// Round 1
// baseline (4451.549 us; speedup 1.0000x reference)
//
#include <hip/hip_runtime.h>
#include <hip/hip_bf16.h>

#define NN 100000
#define EE 1600000
#define DD 128
#define EPSc 0.1f

// ---------------- CSR build kernels ----------------

__global__ __launch_bounds__(256) void count_deg_kernel(const int* __restrict__ dst,
                                                        int* __restrict__ ideg, int e_cnt) {
    int e = blockIdx.x * 256 + threadIdx.x;
    if (e < e_cnt) atomicAdd(&ideg[dst[e]], 1);
}

__global__ __launch_bounds__(256) void dinv_kernel(const int* __restrict__ ideg,
                                                   float* __restrict__ dinv, int n) {
    int i = blockIdx.x * 256 + threadIdx.x;
    if (i < n) {
        int d = ideg[i];
        dinv[i] = (d > 0) ? rsqrtf((float)d) : 0.0f;
    }
}

__global__ __launch_bounds__(1024) void scan_kernel(const int* __restrict__ ideg,
                                                    int* __restrict__ row_ptr,
                                                    int* __restrict__ cursor, int n) {
    __shared__ int sm[1024];
    __shared__ int carry;
    if (threadIdx.x == 0) carry = 0;
    __syncthreads();
    for (int base = 0; base < n; base += 1024) {
        int i = base + (int)threadIdx.x;
        int v = (i < n) ? ideg[i] : 0;
        sm[threadIdx.x] = v;
        __syncthreads();
        for (int off = 1; off < 1024; off <<= 1) {
            int t = (threadIdx.x >= (unsigned)off) ? sm[threadIdx.x - off] : 0;
            __syncthreads();
            sm[threadIdx.x] += t;
            __syncthreads();
        }
        int excl = sm[threadIdx.x] - v;
        int c = carry;
        int total = sm[1023];
        __syncthreads();
        if (threadIdx.x == 0) carry = c + total;
        if (i < n) { row_ptr[i] = c + excl; cursor[i] = c + excl; }
        __syncthreads();
    }
    if (threadIdx.x == 0) row_ptr[n] = carry;
}

__global__ __launch_bounds__(256) void fill_csr_kernel(const int* __restrict__ src,
                                                       const int* __restrict__ dst,
                                                       const float* __restrict__ dinv,
                                                       int* __restrict__ cursor,
                                                       int* __restrict__ col,
                                                       float* __restrict__ val, int e_cnt) {
    int e = blockIdx.x * 256 + threadIdx.x;
    if (e < e_cnt) {
        int d = dst[e], s = src[e];
        int pos = atomicAdd(&cursor[d], 1);
        col[pos] = s;
        val[pos] = dinv[s] * dinv[d];
    }
}

// ---------------- propagation: out[i] = sum_e val * xin[col[e]] ----------------

__global__ __launch_bounds__(256) void prop_kernel(const float* __restrict__ xin,
                                                   float* __restrict__ xout,
                                                   const int* __restrict__ row_ptr,
                                                   const int* __restrict__ col,
                                                   const float* __restrict__ val, int n) {
    int wid = (blockIdx.x * 256 + threadIdx.x) >> 6;  // one wave per node
    int lane = threadIdx.x & 63;
    if (wid >= n) return;
    int s = row_ptr[wid];
    int e = row_ptr[wid + 1];
    float a0 = 0.f, a1 = 0.f;
    for (int i = s; i < e; ++i) {
        int c = col[i];
        float v = val[i];
        float2 x = *(const float2*)(xin + (size_t)c * DD + lane * 2);
        a0 = fmaf(v, x.x, a0);
        a1 = fmaf(v, x.y, a1);
    }
    *(float2*)(xout + (size_t)wid * DD + lane * 2) = make_float2(a0, a1);
}

// ---------------- matmul: [n,128] @ [128,128], fused epilogues ----------------
// mode 0: out = A@W
// mode 1: out += A@W
// mode 2: out = base + scale * tanh(Cpart + A@W + bias)
// mode 3: out = A@W + bias

__global__ __launch_bounds__(256) void matmul_kernel(const float* __restrict__ A,
                                                     const float* __restrict__ W,
                                                     const float* __restrict__ bias,
                                                     float* __restrict__ out,
                                                     const float* __restrict__ Cpart,
                                                     const float* __restrict__ base,
                                                     float scale, int mode) {
    __shared__ float Wl[128][128];   // 64 KB
    __shared__ float Al[32][128];    // 16 KB
    int tid = threadIdx.x;

    const float4* Wv = (const float4*)W;
    float4* Wlv = (float4*)&Wl[0][0];
    #pragma unroll
    for (int i = 0; i < 16; ++i) Wlv[tid + i * 256] = Wv[tid + i * 256];

    size_t row0 = (size_t)blockIdx.x * 32;   // N divisible by 32
    const float4* Av = (const float4*)(A + row0 * DD);
    float4* Alv = (float4*)&Al[0][0];
    #pragma unroll
    for (int i = 0; i < 4; ++i) Alv[tid + i * 256] = Av[tid + i * 256];
    __syncthreads();

    int cq = tid & 31;   // 32 col-quads -> cols cq*4 .. cq*4+3
    int rg = tid >> 5;   // 8 row groups -> rows rg*4 .. rg*4+3
    float acc[4][4] = {};
    #pragma unroll 8
    for (int k = 0; k < 128; ++k) {
        float4 w = *(const float4*)&Wl[k][cq * 4];
        #pragma unroll
        for (int i = 0; i < 4; ++i) {
            float a = Al[rg * 4 + i][k];
            acc[i][0] = fmaf(a, w.x, acc[i][0]);
            acc[i][1] = fmaf(a, w.y, acc[i][1]);
            acc[i][2] = fmaf(a, w.z, acc[i][2]);
            acc[i][3] = fmaf(a, w.w, acc[i][3]);
        }
    }

    #pragma unroll
    for (int i = 0; i < 4; ++i) {
        size_t r = row0 + rg * 4 + i;
        float* orow = out + r * DD + cq * 4;
        float4 o = make_float4(acc[i][0], acc[i][1], acc[i][2], acc[i][3]);
        if (mode == 0) {
            *(float4*)orow = o;
        } else if (mode == 1) {
            float4 c = *(const float4*)orow;
            o.x += c.x; o.y += c.y; o.z += c.z; o.w += c.w;
            *(float4*)orow = o;
        } else if (mode == 3) {
            float4 b = *(const float4*)(bias + cq * 4);
            o.x += b.x; o.y += b.y; o.z += b.z; o.w += b.w;
            *(float4*)orow = o;
        } else {
            float4 b = *(const float4*)(bias + cq * 4);
            float4 cp = *(const float4*)(Cpart + r * DD + cq * 4);
            float4 bs = *(const float4*)(base + r * DD + cq * 4);
            o.x = bs.x + scale * tanhf(cp.x + o.x + b.x);
            o.y = bs.y + scale * tanhf(cp.y + o.y + b.y);
            o.z = bs.z + scale * tanhf(cp.z + o.z + b.z);
            o.w = bs.w + scale * tanhf(cp.w + o.w + b.w);
            *(float4*)orow = o;
        }
    }
}

// ---------------- launch ----------------

extern "C" void kernel_launch(void* const* d_in, const int* in_sizes, int n_in,
                              void* d_out, int out_size, void* d_ws, size_t ws_size,
                              hipStream_t stream) {
    const float* x      = (const float*)d_in[0];
    const int*   eidx   = (const int*)d_in[1];
    const float* emb_w  = (const float*)d_in[3];
    const float* emb_b  = (const float*)d_in[4];
    const float* conv_ws = (const float*)d_in[5];   // [3][128][128]
    const float* conv_b = (const float*)d_in[6];
    const float* ro_w   = (const float*)d_in[7];
    const float* ro_b   = (const float*)d_in[8];
    // delta_t (d_in[2]) is the traced constant 4 in the reference

    const int* src = eidx;
    const int* dst = eidx + EE;

    float* y  = (float*)d_out;                   // [N,128]
    float* hm = y + (size_t)NN * DD;             // [N,128] h_middle output slot

    char* p = (char*)d_ws;
    const size_t FB = (size_t)NN * DD * sizeof(float);   // 51.2 MB
    float* h    = (float*)p;            p += FB;
    float* bufA = (float*)p;            p += FB;
    float* bufB = (float*)p;            p += FB;
    float* dinv = (float*)p;            p += (size_t)NN * 4;
    int* ideg    = (int*)p;             p += (size_t)NN * 4;
    int* row_ptr = (int*)p;             p += (size_t)(NN + 1) * 4;
    int* cursor  = (int*)p;             p += (size_t)NN * 4;
    int* col     = (int*)p;             p += (size_t)EE * 4;
    float* val   = (float*)p;           p += (size_t)EE * 4;

    const float* W0 = conv_ws;
    const float* W1 = conv_ws + 128 * 128;
    const float* W2 = conv_ws + 2 * 128 * 128;

    // --- CSR build ---
    hipMemsetAsync(ideg, 0, (size_t)NN * 4, stream);
    count_deg_kernel<<<EE / 256, 256, 0, stream>>>(dst, ideg, EE);
    dinv_kernel<<<(NN + 255) / 256, 256, 0, stream>>>(ideg, dinv, NN);
    scan_kernel<<<1, 1024, 0, stream>>>(ideg, row_ptr, cursor, NN);
    fill_csr_kernel<<<EE / 256, 256, 0, stream>>>(src, dst, dinv, cursor, col, val, EE);

    const int MM_GRID = NN / 32;           // 3125
    const int PROP_GRID = NN * 64 / 256;   // 25000

    float* conv = y;  // use y region as conv scratch until the end

    // h = x @ emb_w + emb_b
    matmul_kernel<<<MM_GRID, 256, 0, stream>>>(x, emb_w, emb_b, h, nullptr, nullptr, 0.f, 3);

    for (int t = 0; t < 4; ++t) {
        // ---- conv = TAGConv(h); h_middle = h + 0.05*tanh(conv) ----
        matmul_kernel<<<MM_GRID, 256, 0, stream>>>(h, W0, nullptr, conv, nullptr, nullptr, 0.f, 0);
        prop_kernel<<<PROP_GRID, 256, 0, stream>>>(h, bufA, row_ptr, col, val, NN);
        matmul_kernel<<<MM_GRID, 256, 0, stream>>>(bufA, W1, nullptr, conv, nullptr, nullptr, 0.f, 1);
        prop_kernel<<<PROP_GRID, 256, 0, stream>>>(bufA, bufB, row_ptr, col, val, NN);
        matmul_kernel<<<MM_GRID, 256, 0, stream>>>(bufB, W2, conv_b, hm, conv, h, 0.5f * EPSc, 2);

        // ---- conv_mid = TAGConv(h_middle); h = h + 0.1*tanh(conv_mid) ----
        matmul_kernel<<<MM_GRID, 256, 0, stream>>>(hm, W0, nullptr, conv, nullptr, nullptr, 0.f, 0);
        prop_kernel<<<PROP_GRID, 256, 0, stream>>>(hm, bufA, row_ptr, col, val, NN);
        matmul_kernel<<<MM_GRID, 256, 0, stream>>>(bufA, W1, nullptr, conv, nullptr, nullptr, 0.f, 1);
        prop_kernel<<<PROP_GRID, 256, 0, stream>>>(bufA, bufB, row_ptr, col, val, NN);
        matmul_kernel<<<MM_GRID, 256, 0, stream>>>(bufB, W2, conv_b, h, conv, h, EPSc, 2);
    }

    // y = h_middle @ ro_w + ro_b   (overwrites conv scratch)
    matmul_kernel<<<MM_GRID, 256, 0, stream>>>(hm, ro_w, ro_b, y, nullptr, nullptr, 0.f, 3);
}

// Round 2
// 4020.691 us; speedup vs baseline: 1.1072x; 1.1072x over previous
//
#include <hip/hip_runtime.h>
#include <hip/hip_bf16.h>

#define NN 100000
#define EE 1600000
#define DD 128
#define EPSc 0.1f

typedef unsigned short bfu;   // bf16 stored as raw ushort

__device__ __forceinline__ float bf2f(bfu s) {
    union { unsigned u; float f; } c; c.u = ((unsigned)s) << 16; return c.f;
}
__device__ __forceinline__ bfu f2bf(float f) {
    union { float f; unsigned u; } c; c.f = f;
    unsigned u = c.u + 0x7fffu + ((c.u >> 16) & 1u);   // RNE
    return (bfu)(u >> 16);
}
struct alignas(8) us4 { bfu a, b, c, d; };

// ---------------- CSR build kernels ----------------

__global__ __launch_bounds__(256) void count_deg_kernel(const int* __restrict__ dst,
                                                        int* __restrict__ ideg, int e_cnt) {
    int e = blockIdx.x * 256 + threadIdx.x;
    if (e < e_cnt) atomicAdd(&ideg[dst[e]], 1);
}

__global__ __launch_bounds__(256) void dinv_kernel(const int* __restrict__ ideg,
                                                   float* __restrict__ dinv, int n) {
    int i = blockIdx.x * 256 + threadIdx.x;
    if (i < n) {
        int d = ideg[i];
        dinv[i] = (d > 0) ? rsqrtf((float)d) : 0.0f;
    }
}

__global__ __launch_bounds__(256) void partial_sum_kernel(const int* __restrict__ ideg,
                                                          int* __restrict__ partials, int n) {
    __shared__ int sm[256];
    int i = blockIdx.x * 256 + threadIdx.x;
    sm[threadIdx.x] = (i < n) ? ideg[i] : 0;
    __syncthreads();
    for (int off = 128; off > 0; off >>= 1) {
        if ((int)threadIdx.x < off) sm[threadIdx.x] += sm[threadIdx.x + off];
        __syncthreads();
    }
    if (threadIdx.x == 0) partials[blockIdx.x] = sm[0];
}

__global__ __launch_bounds__(512) void scan_partials_kernel(int* __restrict__ partials,
                                                            int* __restrict__ row_ptr,
                                                            int nb, int n) {
    __shared__ int sm[512];
    int v = ((int)threadIdx.x < nb) ? partials[threadIdx.x] : 0;
    sm[threadIdx.x] = v;
    __syncthreads();
    for (int off = 1; off < 512; off <<= 1) {
        int t = (threadIdx.x >= (unsigned)off) ? sm[threadIdx.x - off] : 0;
        __syncthreads();
        sm[threadIdx.x] += t;
        __syncthreads();
    }
    if ((int)threadIdx.x < nb) partials[threadIdx.x] = sm[threadIdx.x] - v;  // exclusive
    if (threadIdx.x == 511) row_ptr[n] = sm[511];
}

__global__ __launch_bounds__(256) void scan_block_kernel(const int* __restrict__ ideg,
                                                         const int* __restrict__ partials,
                                                         int* __restrict__ row_ptr,
                                                         int* __restrict__ cursor, int n) {
    __shared__ int sm[256];
    int i = blockIdx.x * 256 + threadIdx.x;
    int v = (i < n) ? ideg[i] : 0;
    sm[threadIdx.x] = v;
    __syncthreads();
    for (int off = 1; off < 256; off <<= 1) {
        int t = (threadIdx.x >= (unsigned)off) ? sm[threadIdx.x - off] : 0;
        __syncthreads();
        sm[threadIdx.x] += t;
        __syncthreads();
    }
    if (i < n) {
        int excl = partials[blockIdx.x] + sm[threadIdx.x] - v;
        row_ptr[i] = excl;
        cursor[i] = excl;
    }
}

__global__ __launch_bounds__(256) void fill_csr_kernel(const int* __restrict__ src,
                                                       const int* __restrict__ dst,
                                                       const float* __restrict__ dinv,
                                                       int* __restrict__ cursor,
                                                       int* __restrict__ col,
                                                       float* __restrict__ val, int e_cnt) {
    int e = blockIdx.x * 256 + threadIdx.x;
    if (e < e_cnt) {
        int d = dst[e], s = src[e];
        int pos = atomicAdd(&cursor[d], 1);
        col[pos] = s;
        val[pos] = dinv[s] * dinv[d];
    }
}

// ---------------- propagation (bf16 in / bf16 out, f32 accum) ----------------

__global__ __launch_bounds__(256) void prop_kernel(const bfu* __restrict__ xin,
                                                   bfu* __restrict__ xout,
                                                   const int* __restrict__ row_ptr,
                                                   const int* __restrict__ col,
                                                   const float* __restrict__ val, int n) {
    int wid = (blockIdx.x * 256 + threadIdx.x) >> 6;  // one wave per node
    int lane = threadIdx.x & 63;
    if (wid >= n) return;
    int s = row_ptr[wid];
    int e = row_ptr[wid + 1];
    float a0 = 0.f, a1 = 0.f;
    for (int i = s; i < e; ++i) {
        int c = col[i];
        float v = val[i];
        unsigned px = *(const unsigned*)(xin + (size_t)c * DD + lane * 2);
        a0 = fmaf(v, bf2f((bfu)px), a0);
        a1 = fmaf(v, bf2f((bfu)(px >> 16)), a1);
    }
    *(unsigned*)(xout + (size_t)wid * DD + lane * 2) =
        (unsigned)f2bf(a0) | ((unsigned)f2bf(a1) << 16);
}

// ---------------- matmul (bf16 A): [n,128] @ [128,128] f32 W, fused epilogues ----------------
// mode 0: out = A@W
// mode 1: out += A@W
// mode 2: out = base + scale * tanh(Cpart + A@W + bias); out16 = bf16(out)
// mode 3: out = A@W + bias

__global__ __launch_bounds__(256) void matmul_bf16_kernel(const bfu* __restrict__ A,
                                                          const float* __restrict__ W,
                                                          const float* __restrict__ bias,
                                                          float* __restrict__ out,
                                                          bfu* __restrict__ out16,
                                                          const float* __restrict__ Cpart,
                                                          const float* __restrict__ base,
                                                          float scale, int mode) {
    __shared__ float Wl[128][128];   // 64 KB
    __shared__ float Al[32][128];    // 16 KB
    int tid = threadIdx.x;

    const float4* Wv = (const float4*)W;
    float4* Wlv = (float4*)&Wl[0][0];
    #pragma unroll
    for (int i = 0; i < 16; ++i) Wlv[tid + i * 256] = Wv[tid + i * 256];

    size_t row0 = (size_t)blockIdx.x * 32;   // N divisible by 32
    const uint4* Av = (const uint4*)(A + row0 * DD);
    float* Alf = &Al[0][0];
    #pragma unroll
    for (int i = 0; i < 2; ++i) {
        uint4 u = Av[tid + i * 256];
        int b = (tid + i * 256) * 8;
        Alf[b + 0] = bf2f((bfu)u.x); Alf[b + 1] = bf2f((bfu)(u.x >> 16));
        Alf[b + 2] = bf2f((bfu)u.y); Alf[b + 3] = bf2f((bfu)(u.y >> 16));
        Alf[b + 4] = bf2f((bfu)u.z); Alf[b + 5] = bf2f((bfu)(u.z >> 16));
        Alf[b + 6] = bf2f((bfu)u.w); Alf[b + 7] = bf2f((bfu)(u.w >> 16));
    }
    __syncthreads();

    int cq = tid & 31;
    int rg = tid >> 5;
    float acc[4][4] = {};
    #pragma unroll 8
    for (int k = 0; k < 128; ++k) {
        float4 w = *(const float4*)&Wl[k][cq * 4];
        #pragma unroll
        for (int i = 0; i < 4; ++i) {
            float a = Al[rg * 4 + i][k];
            acc[i][0] = fmaf(a, w.x, acc[i][0]);
            acc[i][1] = fmaf(a, w.y, acc[i][1]);
            acc[i][2] = fmaf(a, w.z, acc[i][2]);
            acc[i][3] = fmaf(a, w.w, acc[i][3]);
        }
    }

    #pragma unroll
    for (int i = 0; i < 4; ++i) {
        size_t r = row0 + rg * 4 + i;
        float* orow = out + r * DD + cq * 4;
        float4 o = make_float4(acc[i][0], acc[i][1], acc[i][2], acc[i][3]);
        if (mode == 0) {
            *(float4*)orow = o;
        } else if (mode == 1) {
            float4 c = *(const float4*)orow;
            o.x += c.x; o.y += c.y; o.z += c.z; o.w += c.w;
            *(float4*)orow = o;
        } else if (mode == 3) {
            float4 b = *(const float4*)(bias + cq * 4);
            o.x += b.x; o.y += b.y; o.z += b.z; o.w += b.w;
            *(float4*)orow = o;
        } else {
            float4 b = *(const float4*)(bias + cq * 4);
            float4 cp = *(const float4*)(Cpart + r * DD + cq * 4);
            float4 bs = *(const float4*)(base + r * DD + cq * 4);
            o.x = bs.x + scale * tanhf(cp.x + o.x + b.x);
            o.y = bs.y + scale * tanhf(cp.y + o.y + b.y);
            o.z = bs.z + scale * tanhf(cp.z + o.z + b.z);
            o.w = bs.w + scale * tanhf(cp.w + o.w + b.w);
            *(float4*)orow = o;
            us4 q = { f2bf(o.x), f2bf(o.y), f2bf(o.z), f2bf(o.w) };
            *(us4*)(out16 + r * DD + cq * 4) = q;
        }
    }
}

// f32-A matmul (embedding only): out = A@W + bias, out16 = bf16(out)
__global__ __launch_bounds__(256) void matmul_f32_kernel(const float* __restrict__ A,
                                                         const float* __restrict__ W,
                                                         const float* __restrict__ bias,
                                                         float* __restrict__ out,
                                                         bfu* __restrict__ out16) {
    __shared__ float Wl[128][128];
    __shared__ float Al[32][128];
    int tid = threadIdx.x;

    const float4* Wv = (const float4*)W;
    float4* Wlv = (float4*)&Wl[0][0];
    #pragma unroll
    for (int i = 0; i < 16; ++i) Wlv[tid + i * 256] = Wv[tid + i * 256];

    size_t row0 = (size_t)blockIdx.x * 32;
    const float4* Av = (const float4*)(A + row0 * DD);
    float4* Alv = (float4*)&Al[0][0];
    #pragma unroll
    for (int i = 0; i < 4; ++i) Alv[tid + i * 256] = Av[tid + i * 256];
    __syncthreads();

    int cq = tid & 31;
    int rg = tid >> 5;
    float acc[4][4] = {};
    #pragma unroll 8
    for (int k = 0; k < 128; ++k) {
        float4 w = *(const float4*)&Wl[k][cq * 4];
        #pragma unroll
        for (int i = 0; i < 4; ++i) {
            float a = Al[rg * 4 + i][k];
            acc[i][0] = fmaf(a, w.x, acc[i][0]);
            acc[i][1] = fmaf(a, w.y, acc[i][1]);
            acc[i][2] = fmaf(a, w.z, acc[i][2]);
            acc[i][3] = fmaf(a, w.w, acc[i][3]);
        }
    }

    #pragma unroll
    for (int i = 0; i < 4; ++i) {
        size_t r = row0 + rg * 4 + i;
        float4 b = *(const float4*)(bias + cq * 4);
        float4 o = make_float4(acc[i][0] + b.x, acc[i][1] + b.y,
                               acc[i][2] + b.z, acc[i][3] + b.w);
        *(float4*)(out + r * DD + cq * 4) = o;
        us4 q = { f2bf(o.x), f2bf(o.y), f2bf(o.z), f2bf(o.w) };
        *(us4*)(out16 + r * DD + cq * 4) = q;
    }
}

// ---------------- launch ----------------

extern "C" void kernel_launch(void* const* d_in, const int* in_sizes, int n_in,
                              void* d_out, int out_size, void* d_ws, size_t ws_size,
                              hipStream_t stream) {
    const float* x      = (const float*)d_in[0];
    const int*   eidx   = (const int*)d_in[1];
    const float* emb_w  = (const float*)d_in[3];
    const float* emb_b  = (const float*)d_in[4];
    const float* conv_ws = (const float*)d_in[5];   // [3][128][128]
    const float* conv_b = (const float*)d_in[6];
    const float* ro_w   = (const float*)d_in[7];
    const float* ro_b   = (const float*)d_in[8];
    // delta_t (d_in[2]) is the traced constant 4 in the reference

    const int* src = eidx;
    const int* dst = eidx + EE;

    float* y  = (float*)d_out;                   // [N,128]
    float* hm = y + (size_t)NN * DD;             // [N,128] h_middle output slot

    char* p = (char*)d_ws;
    const size_t FB  = (size_t)NN * DD * sizeof(float);   // 51.2 MB
    const size_t FB2 = (size_t)NN * DD * sizeof(bfu);     // 25.6 MB
    float* h    = (float*)p;            p += FB;
    bfu* h16    = (bfu*)p;              p += FB2;
    bfu* hm16   = (bfu*)p;              p += FB2;
    bfu* bufA   = (bfu*)p;              p += FB2;
    bfu* bufB   = (bfu*)p;              p += FB2;
    float* dinv = (float*)p;            p += (size_t)NN * 4;
    int* ideg    = (int*)p;             p += (size_t)NN * 4;
    int* row_ptr = (int*)p;             p += (size_t)(NN + 1) * 4;
    int* cursor  = (int*)p;             p += (size_t)NN * 4;
    int* partials = (int*)p;            p += (size_t)512 * 4;
    int* col     = (int*)p;             p += (size_t)EE * 4;
    float* val   = (float*)p;           p += (size_t)EE * 4;

    const float* W0 = conv_ws;
    const float* W1 = conv_ws + 128 * 128;
    const float* W2 = conv_ws + 2 * 128 * 128;

    const int NB = (NN + 255) / 256;   // 391

    // --- CSR build ---
    hipMemsetAsync(ideg, 0, (size_t)NN * 4, stream);
    count_deg_kernel<<<EE / 256, 256, 0, stream>>>(dst, ideg, EE);
    dinv_kernel<<<NB, 256, 0, stream>>>(ideg, dinv, NN);
    partial_sum_kernel<<<NB, 256, 0, stream>>>(ideg, partials, NN);
    scan_partials_kernel<<<1, 512, 0, stream>>>(partials, row_ptr, NB, NN);
    scan_block_kernel<<<NB, 256, 0, stream>>>(ideg, partials, row_ptr, cursor, NN);
    fill_csr_kernel<<<EE / 256, 256, 0, stream>>>(src, dst, dinv, cursor, col, val, EE);

    const int MM_GRID = NN / 32;           // 3125
    const int PROP_GRID = NN * 64 / 256;   // 25000

    float* conv = y;  // y region doubles as conv scratch until the end

    // h = x @ emb_w + emb_b  (also h16)
    matmul_f32_kernel<<<MM_GRID, 256, 0, stream>>>(x, emb_w, emb_b, h, h16);

    for (int t = 0; t < 4; ++t) {
        // ---- conv = TAGConv(h); h_middle = h + 0.05*tanh(conv) ----
        matmul_bf16_kernel<<<MM_GRID, 256, 0, stream>>>(h16, W0, nullptr, conv, nullptr, nullptr, nullptr, 0.f, 0);
        prop_kernel<<<PROP_GRID, 256, 0, stream>>>(h16, bufA, row_ptr, col, val, NN);
        matmul_bf16_kernel<<<MM_GRID, 256, 0, stream>>>(bufA, W1, nullptr, conv, nullptr, nullptr, nullptr, 0.f, 1);
        prop_kernel<<<PROP_GRID, 256, 0, stream>>>(bufA, bufB, row_ptr, col, val, NN);
        matmul_bf16_kernel<<<MM_GRID, 256, 0, stream>>>(bufB, W2, conv_b, hm, hm16, conv, h, 0.5f * EPSc, 2);

        // ---- conv_mid = TAGConv(h_middle); h = h + 0.1*tanh(conv_mid) ----
        matmul_bf16_kernel<<<MM_GRID, 256, 0, stream>>>(hm16, W0, nullptr, conv, nullptr, nullptr, nullptr, 0.f, 0);
        prop_kernel<<<PROP_GRID, 256, 0, stream>>>(hm16, bufA, row_ptr, col, val, NN);
        matmul_bf16_kernel<<<MM_GRID, 256, 0, stream>>>(bufA, W1, nullptr, conv, nullptr, nullptr, nullptr, 0.f, 1);
        prop_kernel<<<PROP_GRID, 256, 0, stream>>>(bufA, bufB, row_ptr, col, val, NN);
        matmul_bf16_kernel<<<MM_GRID, 256, 0, stream>>>(bufB, W2, conv_b, h, h16, conv, h, EPSc, 2);
    }

    // y = h_middle @ ro_w + ro_b  (overwrites conv scratch)
    matmul_bf16_kernel<<<MM_GRID, 256, 0, stream>>>(hm16, ro_w, ro_b, y, nullptr, nullptr, nullptr, 0.f, 3);
}

// Round 3
// 1841.431 us; speedup vs baseline: 2.4174x; 2.1835x over previous
//
#include <hip/hip_runtime.h>
#include <hip/hip_bf16.h>

#define NN 100000
#define EE 1600000
#define DD 128
#define EPSc 0.1f

typedef unsigned short bfu;
typedef __attribute__((ext_vector_type(8))) short short8;   // 8 bf16 = 4 VGPRs
typedef __attribute__((ext_vector_type(4))) float f32x4;

__device__ __forceinline__ float bf2f(bfu s) {
    union { unsigned u; float f; } c; c.u = ((unsigned)s) << 16; return c.f;
}
__device__ __forceinline__ bfu f2bf(float f) {
    union { float f; unsigned u; } c; c.f = f;
    unsigned u = c.u + 0x7fffu + ((c.u >> 16) & 1u);   // RNE
    return (bfu)(u >> 16);
}
struct alignas(8) us4 { bfu a, b, c, d; };

// ---------------- CSR build ----------------

__global__ __launch_bounds__(256) void count_deg_kernel(const int* __restrict__ dst,
                                                        int* __restrict__ ideg, int e_cnt) {
    int e = blockIdx.x * 256 + threadIdx.x;
    if (e < e_cnt) atomicAdd(&ideg[dst[e]], 1);
}

__global__ __launch_bounds__(256) void dinv_kernel(const int* __restrict__ ideg,
                                                   float* __restrict__ dinv, int n) {
    int i = blockIdx.x * 256 + threadIdx.x;
    if (i < n) {
        int d = ideg[i];
        dinv[i] = (d > 0) ? rsqrtf((float)d) : 0.0f;
    }
}

__global__ __launch_bounds__(256) void partial_sum_kernel(const int* __restrict__ ideg,
                                                          int* __restrict__ partials, int n) {
    __shared__ int sm[256];
    int i = blockIdx.x * 256 + threadIdx.x;
    sm[threadIdx.x] = (i < n) ? ideg[i] : 0;
    __syncthreads();
    for (int off = 128; off > 0; off >>= 1) {
        if ((int)threadIdx.x < off) sm[threadIdx.x] += sm[threadIdx.x + off];
        __syncthreads();
    }
    if (threadIdx.x == 0) partials[blockIdx.x] = sm[0];
}

__global__ __launch_bounds__(512) void scan_partials_kernel(int* __restrict__ partials,
                                                            int* __restrict__ row_ptr,
                                                            int nb, int n) {
    __shared__ int sm[512];
    int v = ((int)threadIdx.x < nb) ? partials[threadIdx.x] : 0;
    sm[threadIdx.x] = v;
    __syncthreads();
    for (int off = 1; off < 512; off <<= 1) {
        int t = (threadIdx.x >= (unsigned)off) ? sm[threadIdx.x - off] : 0;
        __syncthreads();
        sm[threadIdx.x] += t;
        __syncthreads();
    }
    if ((int)threadIdx.x < nb) partials[threadIdx.x] = sm[threadIdx.x] - v;
    if (threadIdx.x == 511) row_ptr[n] = sm[511];
}

__global__ __launch_bounds__(256) void scan_block_kernel(const int* __restrict__ ideg,
                                                         const int* __restrict__ partials,
                                                         int* __restrict__ row_ptr,
                                                         int* __restrict__ cursor, int n) {
    __shared__ int sm[256];
    int i = blockIdx.x * 256 + threadIdx.x;
    int v = (i < n) ? ideg[i] : 0;
    sm[threadIdx.x] = v;
    __syncthreads();
    for (int off = 1; off < 256; off <<= 1) {
        int t = (threadIdx.x >= (unsigned)off) ? sm[threadIdx.x - off] : 0;
        __syncthreads();
        sm[threadIdx.x] += t;
        __syncthreads();
    }
    if (i < n) {
        int excl = partials[blockIdx.x] + sm[threadIdx.x] - v;
        row_ptr[i] = excl;
        cursor[i] = excl;
    }
}

__global__ __launch_bounds__(256) void fill_csr_kernel(const int* __restrict__ src,
                                                       const int* __restrict__ dst,
                                                       const float* __restrict__ dinv,
                                                       int* __restrict__ cursor,
                                                       uint2* __restrict__ cv, int e_cnt) {
    int e = blockIdx.x * 256 + threadIdx.x;
    if (e < e_cnt) {
        int d = dst[e], s = src[e];
        int pos = atomicAdd(&cursor[d], 1);
        cv[pos] = make_uint2((unsigned)s, __float_as_uint(dinv[s] * dinv[d]));
    }
}

// ------------- weight -> bf16 MFMA-fragment-order transform -------------
// For element (k,n): nt=n>>4, ks=k>>5, kg=(k>>3)&3, j=k&7, l=kg*16+(n&15)
// flat = ((nt*4+ks)*64 + l)*8 + j   -> wave reads 1KB linear per MFMA

__global__ __launch_bounds__(256) void wfrag_kernel(const float* __restrict__ conv_ws,
                                                    const float* __restrict__ ro_w,
                                                    bfu* __restrict__ Wf) {
    int m = blockIdx.x;   // 0..3
    const float* W = (m < 3) ? conv_ws + m * 16384 : ro_w;
    bfu* T = Wf + m * 16384;
    for (int j = 0; j < 64; ++j) {
        int i = threadIdx.x + j * 256;       // i = k*128 + n
        int k = i >> 7, n = i & 127;
        int nt = n >> 4, ks = k >> 5, kg = (k >> 3) & 3, jj = k & 7;
        int l = kg * 16 + (n & 15);
        int flat = ((nt * 4 + ks) * 64 + l) * 8 + jj;
        T[flat] = f2bf(W[i]);
    }
}

// ---------------- propagation: 16 lanes/edge, 8 gathers in flight ----------------

__device__ __forceinline__ void acc8(uint4 u, float v, float* acc) {
    acc[0] = fmaf(v, bf2f((bfu)u.x), acc[0]);
    acc[1] = fmaf(v, bf2f((bfu)(u.x >> 16)), acc[1]);
    acc[2] = fmaf(v, bf2f((bfu)u.y), acc[2]);
    acc[3] = fmaf(v, bf2f((bfu)(u.y >> 16)), acc[3]);
    acc[4] = fmaf(v, bf2f((bfu)u.z), acc[4]);
    acc[5] = fmaf(v, bf2f((bfu)(u.z >> 16)), acc[5]);
    acc[6] = fmaf(v, bf2f((bfu)u.w), acc[6]);
    acc[7] = fmaf(v, bf2f((bfu)(u.w >> 16)), acc[7]);
}

__global__ __launch_bounds__(256) void prop_kernel(const bfu* __restrict__ xin,
                                                   bfu* __restrict__ xout,
                                                   const int* __restrict__ row_ptr,
                                                   const uint2* __restrict__ cv, int n) {
    int wid = (blockIdx.x * 256 + threadIdx.x) >> 6;  // one wave per node
    int lane = threadIdx.x & 63;
    if (wid >= n) return;
    int s = row_ptr[wid];
    int e = row_ptr[wid + 1];
    int g = lane >> 4;        // edge slot 0..3
    int li = lane & 15;       // 16 lanes cover the 128-dim row (8 dims each)
    float acc[8] = {0.f, 0.f, 0.f, 0.f, 0.f, 0.f, 0.f, 0.f};
    for (int ib = s; ib < e; ib += 8) {
        int i0 = ib + g;
        int i1 = ib + 4 + g;
        uint2 c0 = (i0 < e) ? cv[i0] : make_uint2(0u, 0u);
        uint2 c1 = (i1 < e) ? cv[i1] : make_uint2(0u, 0u);
        uint4 x0 = *(const uint4*)(xin + (size_t)c0.x * DD + li * 8);
        uint4 x1 = *(const uint4*)(xin + (size_t)c1.x * DD + li * 8);
        float v0 = __uint_as_float(c0.y);
        float v1 = __uint_as_float(c1.y);
        acc8(x0, v0, acc);
        acc8(x1, v1, acc);
    }
    #pragma unroll
    for (int k = 0; k < 8; ++k) {
        acc[k] += __shfl_xor(acc[k], 16);
        acc[k] += __shfl_xor(acc[k], 32);
    }
    if (g == 0) {
        uint4 o;
        o.x = (unsigned)f2bf(acc[0]) | ((unsigned)f2bf(acc[1]) << 16);
        o.y = (unsigned)f2bf(acc[2]) | ((unsigned)f2bf(acc[3]) << 16);
        o.z = (unsigned)f2bf(acc[4]) | ((unsigned)f2bf(acc[5]) << 16);
        o.w = (unsigned)f2bf(acc[6]) | ((unsigned)f2bf(acc[7]) << 16);
        *(uint4*)(xout + (size_t)wid * DD + li * 8) = o;
    }
}

// ---------------- MFMA matmul: acc = sum_m A_m @ W_m, fused epilogue ----------------
// TANH: out = base + scale*tanh(acc + bias); out16 = bf16(out)
// else: out = acc + bias

template <int NMAT, bool TANH>
__global__ __launch_bounds__(256) void mfma_mm_kernel(const bfu* __restrict__ A0,
                                                      const bfu* __restrict__ A1,
                                                      const bfu* __restrict__ A2,
                                                      const bfu* __restrict__ Wf,
                                                      const float* __restrict__ bias,
                                                      const float* __restrict__ base,
                                                      float* __restrict__ out,
                                                      bfu* __restrict__ out16,
                                                      float scale) {
    int tid = threadIdx.x;
    int wave = tid >> 6, lane = tid & 63;
    int r0 = blockIdx.x * 64 + wave * 16;
    int li = lane & 15, kg = lane >> 4;
    int rowA = r0 + li;
    bool rv = rowA < NN;
    size_t abyte = (size_t)(rv ? rowA : 0) * DD * 2;   // bytes

    const bfu* As[3] = {A0, A1, A2};
    short8 a[NMAT][4];
    #pragma unroll
    for (int m = 0; m < NMAT; ++m) {
        #pragma unroll
        for (int ks = 0; ks < 4; ++ks) {
            short8 t = *(const short8*)((const char*)As[m] + abyte + ks * 64 + kg * 16);
            if (!rv) t = (short8)0;
            a[m][ks] = t;
        }
    }

    const short8* Bp = (const short8*)Wf;   // [NMAT][32][64] short8
    f32x4 acc[8];
    #pragma unroll
    for (int nt = 0; nt < 8; ++nt) acc[nt] = (f32x4)(0.f);
    #pragma unroll
    for (int nt = 0; nt < 8; ++nt) {
        #pragma unroll
        for (int m = 0; m < NMAT; ++m) {
            #pragma unroll
            for (int ks = 0; ks < 4; ++ks) {
                short8 b = Bp[m * 2048 + (nt * 4 + ks) * 64 + lane];
                acc[nt] = __builtin_amdgcn_mfma_f32_16x16x32_bf16(a[m][ks], b, acc[nt], 0, 0, 0);
            }
        }
    }

    #pragma unroll
    for (int nt = 0; nt < 8; ++nt) {
        int cc = nt * 16 + li;
        float bv = bias[cc];
        #pragma unroll
        for (int rg = 0; rg < 4; ++rg) {
            int rr = r0 + kg * 4 + rg;
            if (rr < NN) {
                size_t off = (size_t)rr * DD + cc;
                float o = acc[nt][rg];
                if (TANH) {
                    float ov = base[off] + scale * tanhf(o + bv);
                    out[off] = ov;
                    out16[off] = f2bf(ov);
                } else {
                    out[off] = o + bv;
                }
            }
        }
    }
}

// ---------------- f32 matmul for embedding: out = A@W + b, out16 = bf16 ----------------

__global__ __launch_bounds__(256) void matmul_f32_kernel(const float* __restrict__ A,
                                                         const float* __restrict__ W,
                                                         const float* __restrict__ bias,
                                                         float* __restrict__ out,
                                                         bfu* __restrict__ out16) {
    __shared__ float Wl[128][128];
    __shared__ float Al[32][128];
    int tid = threadIdx.x;

    const float4* Wv = (const float4*)W;
    float4* Wlv = (float4*)&Wl[0][0];
    #pragma unroll
    for (int i = 0; i < 16; ++i) Wlv[tid + i * 256] = Wv[tid + i * 256];

    size_t row0 = (size_t)blockIdx.x * 32;
    const float4* Av = (const float4*)(A + row0 * DD);
    float4* Alv = (float4*)&Al[0][0];
    #pragma unroll
    for (int i = 0; i < 4; ++i) Alv[tid + i * 256] = Av[tid + i * 256];
    __syncthreads();

    int cq = tid & 31;
    int rg = tid >> 5;
    float acc[4][4] = {};
    #pragma unroll 8
    for (int k = 0; k < 128; ++k) {
        float4 w = *(const float4*)&Wl[k][cq * 4];
        #pragma unroll
        for (int i = 0; i < 4; ++i) {
            float a = Al[rg * 4 + i][k];
            acc[i][0] = fmaf(a, w.x, acc[i][0]);
            acc[i][1] = fmaf(a, w.y, acc[i][1]);
            acc[i][2] = fmaf(a, w.z, acc[i][2]);
            acc[i][3] = fmaf(a, w.w, acc[i][3]);
        }
    }

    #pragma unroll
    for (int i = 0; i < 4; ++i) {
        size_t r = row0 + rg * 4 + i;
        float4 b = *(const float4*)(bias + cq * 4);
        float4 o = make_float4(acc[i][0] + b.x, acc[i][1] + b.y,
                               acc[i][2] + b.z, acc[i][3] + b.w);
        *(float4*)(out + r * DD + cq * 4) = o;
        us4 q = { f2bf(o.x), f2bf(o.y), f2bf(o.z), f2bf(o.w) };
        *(us4*)(out16 + r * DD + cq * 4) = q;
    }
}

// ---------------- launch ----------------

extern "C" void kernel_launch(void* const* d_in, const int* in_sizes, int n_in,
                              void* d_out, int out_size, void* d_ws, size_t ws_size,
                              hipStream_t stream) {
    const float* x      = (const float*)d_in[0];
    const int*   eidx   = (const int*)d_in[1];
    const float* emb_w  = (const float*)d_in[3];
    const float* emb_b  = (const float*)d_in[4];
    const float* conv_ws = (const float*)d_in[5];
    const float* conv_b = (const float*)d_in[6];
    const float* ro_w   = (const float*)d_in[7];
    const float* ro_b   = (const float*)d_in[8];

    const int* src = eidx;
    const int* dst = eidx + EE;

    float* y  = (float*)d_out;                   // [N,128]
    float* hm = y + (size_t)NN * DD;             // [N,128] h_middle output

    char* p = (char*)d_ws;
    const size_t FB  = (size_t)NN * DD * sizeof(float);
    const size_t FB2 = (size_t)NN * DD * sizeof(bfu);
    float* h    = (float*)p;            p += FB;
    bfu* h16    = (bfu*)p;              p += FB2;
    bfu* hm16   = (bfu*)p;              p += FB2;
    bfu* bufA   = (bfu*)p;              p += FB2;
    bfu* bufB   = (bfu*)p;              p += FB2;
    float* dinv = (float*)p;            p += (size_t)NN * 4;
    int* ideg    = (int*)p;             p += (size_t)NN * 4;
    int* row_ptr = (int*)p;             p += (size_t)(NN + 1) * 4;
    int* cursor  = (int*)p;             p += (size_t)NN * 4;
    int* partials = (int*)p;            p += (size_t)512 * 4;
    bfu* Wf      = (bfu*)p;             p += (size_t)4 * 16384 * sizeof(bfu);
    uint2* cv    = (uint2*)p;           p += (size_t)EE * 8;

    const int NB = (NN + 255) / 256;   // 391

    hipMemsetAsync(ideg, 0, (size_t)NN * 4, stream);
    count_deg_kernel<<<EE / 256, 256, 0, stream>>>(dst, ideg, EE);
    dinv_kernel<<<NB, 256, 0, stream>>>(ideg, dinv, NN);
    partial_sum_kernel<<<NB, 256, 0, stream>>>(ideg, partials, NN);
    scan_partials_kernel<<<1, 512, 0, stream>>>(partials, row_ptr, NB, NN);
    scan_block_kernel<<<NB, 256, 0, stream>>>(ideg, partials, row_ptr, cursor, NN);
    fill_csr_kernel<<<EE / 256, 256, 0, stream>>>(src, dst, dinv, cursor, cv, EE);
    wfrag_kernel<<<4, 256, 0, stream>>>(conv_ws, ro_w, Wf);

    const int MM_GRID  = (NN + 63) / 64;     // 1563 (tail-guarded)
    const int PROP_GRID = NN * 64 / 256;     // 25000

    // h = x @ emb_w + emb_b (f32 path for accuracy)
    matmul_f32_kernel<<<NN / 32, 256, 0, stream>>>(x, emb_w, emb_b, h, h16);

    for (int t = 0; t < 4; ++t) {
        // conv(h) fused: hm = h + 0.05*tanh(h@W0 + (Ph)@W1 + (PPh)@W2 + b)
        prop_kernel<<<PROP_GRID, 256, 0, stream>>>(h16, bufA, row_ptr, cv, NN);
        prop_kernel<<<PROP_GRID, 256, 0, stream>>>(bufA, bufB, row_ptr, cv, NN);
        mfma_mm_kernel<3, true><<<MM_GRID, 256, 0, stream>>>(
            h16, bufA, bufB, Wf, conv_b, h, hm, hm16, 0.5f * EPSc);

        // conv(hm) fused: h = h + 0.1*tanh(hm@W0 + (Phm)@W1 + (PPhm)@W2 + b)
        prop_kernel<<<PROP_GRID, 256, 0, stream>>>(hm16, bufA, row_ptr, cv, NN);
        prop_kernel<<<PROP_GRID, 256, 0, stream>>>(bufA, bufB, row_ptr, cv, NN);
        mfma_mm_kernel<3, true><<<MM_GRID, 256, 0, stream>>>(
            hm16, bufA, bufB, Wf, conv_b, h, h, h16, EPSc);
    }

    // y = h_middle @ ro_w + ro_b
    mfma_mm_kernel<1, false><<<MM_GRID, 256, 0, stream>>>(
        hm16, nullptr, nullptr, Wf + 3 * 16384, ro_b, nullptr, y, nullptr, 0.f);
}

// Round 4
// 1662.460 us; speedup vs baseline: 2.6777x; 1.1077x over previous
//
#include <hip/hip_runtime.h>
#include <hip/hip_bf16.h>

#define NN 100000
#define EE 1600000
#define DD 128
#define EPSc 0.1f

typedef unsigned short bfu;
typedef __attribute__((ext_vector_type(8))) short short8;   // 8 bf16 = 4 VGPRs
typedef __attribute__((ext_vector_type(4))) float f32x4;
typedef __attribute__((ext_vector_type(2))) float f32x2;

__device__ __forceinline__ float bf2f(bfu s) {
    union { unsigned u; float f; } c; c.u = ((unsigned)s) << 16; return c.f;
}
__device__ __forceinline__ bfu f2bf(float f) {
    union { float f; unsigned u; } c; c.f = f;
    unsigned u = c.u + 0x7fffu + ((c.u >> 16) & 1u);   // RNE
    return (bfu)(u >> 16);
}
// pack 4 f32 -> 4 fp8 (OCP e4m3) bytes in one dword
__device__ __forceinline__ unsigned pk8(float a, float b, float c, float d) {
    int r = 0;
    r = __builtin_amdgcn_cvt_pk_fp8_f32(a, b, r, false);
    r = __builtin_amdgcn_cvt_pk_fp8_f32(c, d, r, true);
    return (unsigned)r;
}
__device__ __forceinline__ unsigned char enc8(float a) {
    return (unsigned char)(__builtin_amdgcn_cvt_pk_fp8_f32(a, a, 0, false) & 0xFF);
}

// ---------------- CSR build ----------------

__global__ __launch_bounds__(256) void count_deg_kernel(const int* __restrict__ dst,
                                                        int* __restrict__ ideg, int e_cnt) {
    int e = blockIdx.x * 256 + threadIdx.x;
    if (e < e_cnt) atomicAdd(&ideg[dst[e]], 1);
}

__global__ __launch_bounds__(256) void dinv_kernel(const int* __restrict__ ideg,
                                                   float* __restrict__ dinv, int n) {
    int i = blockIdx.x * 256 + threadIdx.x;
    if (i < n) {
        int d = ideg[i];
        dinv[i] = (d > 0) ? rsqrtf((float)d) : 0.0f;
    }
}

__global__ __launch_bounds__(256) void partial_sum_kernel(const int* __restrict__ ideg,
                                                          int* __restrict__ partials, int n) {
    __shared__ int sm[256];
    int i = blockIdx.x * 256 + threadIdx.x;
    sm[threadIdx.x] = (i < n) ? ideg[i] : 0;
    __syncthreads();
    for (int off = 128; off > 0; off >>= 1) {
        if ((int)threadIdx.x < off) sm[threadIdx.x] += sm[threadIdx.x + off];
        __syncthreads();
    }
    if (threadIdx.x == 0) partials[blockIdx.x] = sm[0];
}

__global__ __launch_bounds__(512) void scan_partials_kernel(int* __restrict__ partials,
                                                            int* __restrict__ row_ptr,
                                                            int nb, int n) {
    __shared__ int sm[512];
    int v = ((int)threadIdx.x < nb) ? partials[threadIdx.x] : 0;
    sm[threadIdx.x] = v;
    __syncthreads();
    for (int off = 1; off < 512; off <<= 1) {
        int t = (threadIdx.x >= (unsigned)off) ? sm[threadIdx.x - off] : 0;
        __syncthreads();
        sm[threadIdx.x] += t;
        __syncthreads();
    }
    if ((int)threadIdx.x < nb) partials[threadIdx.x] = sm[threadIdx.x] - v;
    if (threadIdx.x == 511) row_ptr[n] = sm[511];
}

__global__ __launch_bounds__(256) void scan_block_kernel(const int* __restrict__ ideg,
                                                         const int* __restrict__ partials,
                                                         int* __restrict__ row_ptr,
                                                         int* __restrict__ cursor, int n) {
    __shared__ int sm[256];
    int i = blockIdx.x * 256 + threadIdx.x;
    int v = (i < n) ? ideg[i] : 0;
    sm[threadIdx.x] = v;
    __syncthreads();
    for (int off = 1; off < 256; off <<= 1) {
        int t = (threadIdx.x >= (unsigned)off) ? sm[threadIdx.x - off] : 0;
        __syncthreads();
        sm[threadIdx.x] += t;
        __syncthreads();
    }
    if (i < n) {
        int excl = partials[blockIdx.x] + sm[threadIdx.x] - v;
        row_ptr[i] = excl;
        cursor[i] = excl;
    }
}

// packed edge: top 15 bits = f32 val bits[31:17] (sign 0), low 17 bits = col
__global__ __launch_bounds__(256) void fill_csr_kernel(const int* __restrict__ src,
                                                       const int* __restrict__ dst,
                                                       const float* __restrict__ dinv,
                                                       int* __restrict__ cursor,
                                                       unsigned* __restrict__ cvp, int e_cnt) {
    int e = blockIdx.x * 256 + threadIdx.x;
    if (e < e_cnt) {
        int d = dst[e], s = src[e];
        int pos = atomicAdd(&cursor[d], 1);
        unsigned vb = __float_as_uint(dinv[s] * dinv[d]);
        unsigned r = vb + 0xFFFFu + ((vb >> 17) & 1u);   // RNE to 15-bit float
        cvp[pos] = (r & 0xFFFE0000u) | (unsigned)s;
    }
}

// ------------- weight -> bf16 MFMA-fragment-order transform -------------

__global__ __launch_bounds__(256) void wfrag_kernel(const float* __restrict__ conv_ws,
                                                    const float* __restrict__ ro_w,
                                                    bfu* __restrict__ Wf) {
    int m = blockIdx.x;   // 0..3
    const float* W = (m < 3) ? conv_ws + m * 16384 : ro_w;
    bfu* T = Wf + m * 16384;
    for (int j = 0; j < 64; ++j) {
        int i = threadIdx.x + j * 256;       // i = k*128 + n
        int k = i >> 7, n = i & 127;
        int nt = n >> 4, ks = k >> 5, kg = (k >> 3) & 3, jj = k & 7;
        int l = kg * 16 + (n & 15);
        int flat = ((nt * 4 + ks) * 64 + l) * 8 + jj;
        T[flat] = f2bf(W[i]);
    }
}

// ---------------- propagation (fp8 in; bf16 [+fp8] out; f32 accum) ----------------

__device__ __forceinline__ void acc8f8(uint2 u, float v, float* acc) {
    f32x2 p0 = __builtin_amdgcn_cvt_pk_f32_fp8((int)u.x, false);
    f32x2 p1 = __builtin_amdgcn_cvt_pk_f32_fp8((int)u.x, true);
    f32x2 p2 = __builtin_amdgcn_cvt_pk_f32_fp8((int)u.y, false);
    f32x2 p3 = __builtin_amdgcn_cvt_pk_f32_fp8((int)u.y, true);
    acc[0] = fmaf(v, p0[0], acc[0]); acc[1] = fmaf(v, p0[1], acc[1]);
    acc[2] = fmaf(v, p1[0], acc[2]); acc[3] = fmaf(v, p1[1], acc[3]);
    acc[4] = fmaf(v, p2[0], acc[4]); acc[5] = fmaf(v, p2[1], acc[5]);
    acc[6] = fmaf(v, p3[0], acc[6]); acc[7] = fmaf(v, p3[1], acc[7]);
}

template <bool W8>
__global__ __launch_bounds__(256) void prop_kernel(const unsigned char* __restrict__ xin8,
                                                   bfu* __restrict__ out16,
                                                   unsigned char* __restrict__ out8,
                                                   const int* __restrict__ row_ptr,
                                                   const unsigned* __restrict__ cvp, int n) {
    int wid = (blockIdx.x * 256 + threadIdx.x) >> 6;  // one wave per node
    int lane = threadIdx.x & 63;
    if (wid >= n) return;
    int s = row_ptr[wid];
    int e = row_ptr[wid + 1];
    int g = lane >> 4;        // edge slot 0..3
    int li = lane & 15;       // 16 lanes cover 128 dims, 8 per lane (8 bytes fp8)
    float acc[8] = {0.f, 0.f, 0.f, 0.f, 0.f, 0.f, 0.f, 0.f};
    for (int ib = s; ib < e; ib += 8) {
        int i0 = ib + g;
        int i1 = ib + 4 + g;
        uint2 x0 = make_uint2(0u, 0u), x1 = make_uint2(0u, 0u);
        float v0 = 0.f, v1 = 0.f;
        if (i0 < e) {
            unsigned c = cvp[i0];
            v0 = __uint_as_float(c & 0xFFFE0000u);
            x0 = *(const uint2*)(xin8 + (size_t)(c & 0x1FFFFu) * DD + li * 8);
        }
        if (i1 < e) {
            unsigned c = cvp[i1];
            v1 = __uint_as_float(c & 0xFFFE0000u);
            x1 = *(const uint2*)(xin8 + (size_t)(c & 0x1FFFFu) * DD + li * 8);
        }
        acc8f8(x0, v0, acc);
        acc8f8(x1, v1, acc);
    }
    #pragma unroll
    for (int k = 0; k < 8; ++k) {
        acc[k] += __shfl_xor(acc[k], 16);
        acc[k] += __shfl_xor(acc[k], 32);
    }
    if (g == 0) {
        uint4 o;
        o.x = (unsigned)f2bf(acc[0]) | ((unsigned)f2bf(acc[1]) << 16);
        o.y = (unsigned)f2bf(acc[2]) | ((unsigned)f2bf(acc[3]) << 16);
        o.z = (unsigned)f2bf(acc[4]) | ((unsigned)f2bf(acc[5]) << 16);
        o.w = (unsigned)f2bf(acc[6]) | ((unsigned)f2bf(acc[7]) << 16);
        *(uint4*)(out16 + (size_t)wid * DD + li * 8) = o;
        if (W8) {
            uint2 q;
            q.x = pk8(acc[0], acc[1], acc[2], acc[3]);
            q.y = pk8(acc[4], acc[5], acc[6], acc[7]);
            *(uint2*)(out8 + (size_t)wid * DD + li * 8) = q;
        }
    }
}

// ---------------- MFMA matmul: acc = sum_m A_m @ W_m, fused epilogue ----------------
// TANH: v = base + scale*tanh(acc+bias); outf?=v (f32), out16=bf16(v), out8=fp8(v)
// else: out  = acc + bias (f32 only)

template <int NMAT, bool TANH>
__global__ __launch_bounds__(256) void mfma_mm_kernel(const bfu* __restrict__ A0,
                                                      const bfu* __restrict__ A1,
                                                      const bfu* __restrict__ A2,
                                                      const bfu* __restrict__ Wf,
                                                      const float* __restrict__ bias,
                                                      const float* __restrict__ base,
                                                      float* __restrict__ outf,
                                                      bfu* __restrict__ out16,
                                                      unsigned char* __restrict__ out8,
                                                      float scale) {
    int tid = threadIdx.x;
    int wave = tid >> 6, lane = tid & 63;
    int r0 = blockIdx.x * 64 + wave * 16;
    int li = lane & 15, kg = lane >> 4;
    int rowA = r0 + li;
    bool rv = rowA < NN;
    size_t abyte = (size_t)(rv ? rowA : 0) * DD * 2;

    const bfu* As[3] = {A0, A1, A2};
    short8 a[NMAT][4];
    #pragma unroll
    for (int m = 0; m < NMAT; ++m) {
        #pragma unroll
        for (int ks = 0; ks < 4; ++ks) {
            short8 t = *(const short8*)((const char*)As[m] + abyte + ks * 64 + kg * 16);
            if (!rv) t = (short8)0;
            a[m][ks] = t;
        }
    }

    const short8* Bp = (const short8*)Wf;   // [NMAT][32][64] short8
    f32x4 acc[8];
    #pragma unroll
    for (int nt = 0; nt < 8; ++nt) acc[nt] = (f32x4)(0.f);
    #pragma unroll
    for (int nt = 0; nt < 8; ++nt) {
        #pragma unroll
        for (int m = 0; m < NMAT; ++m) {
            #pragma unroll
            for (int ks = 0; ks < 4; ++ks) {
                short8 b = Bp[m * 2048 + (nt * 4 + ks) * 64 + lane];
                acc[nt] = __builtin_amdgcn_mfma_f32_16x16x32_bf16(a[m][ks], b, acc[nt], 0, 0, 0);
            }
        }
    }

    #pragma unroll
    for (int nt = 0; nt < 8; ++nt) {
        int cc = nt * 16 + li;
        float bv = bias[cc];
        #pragma unroll
        for (int rg = 0; rg < 4; ++rg) {
            int rr = r0 + kg * 4 + rg;
            if (rr < NN) {
                size_t off = (size_t)rr * DD + cc;
                float o = acc[nt][rg];
                if (TANH) {
                    float ov = base[off] + scale * tanhf(o + bv);
                    if (outf) outf[off] = ov;
                    out16[off] = f2bf(ov);
                    out8[off] = enc8(ov);
                } else {
                    outf[off] = o + bv;
                }
            }
        }
    }
}

// ---------------- f32 matmul for embedding: h = x@W + b (+bf16, +fp8) ----------------

__global__ __launch_bounds__(256) void matmul_f32_kernel(const float* __restrict__ A,
                                                         const float* __restrict__ W,
                                                         const float* __restrict__ bias,
                                                         float* __restrict__ out,
                                                         bfu* __restrict__ out16,
                                                         unsigned char* __restrict__ out8) {
    __shared__ float Wl[128][128];
    __shared__ float Al[32][128];
    int tid = threadIdx.x;

    const float4* Wv = (const float4*)W;
    float4* Wlv = (float4*)&Wl[0][0];
    #pragma unroll
    for (int i = 0; i < 16; ++i) Wlv[tid + i * 256] = Wv[tid + i * 256];

    size_t row0 = (size_t)blockIdx.x * 32;
    const float4* Av = (const float4*)(A + row0 * DD);
    float4* Alv = (float4*)&Al[0][0];
    #pragma unroll
    for (int i = 0; i < 4; ++i) Alv[tid + i * 256] = Av[tid + i * 256];
    __syncthreads();

    int cq = tid & 31;
    int rg = tid >> 5;
    float acc[4][4] = {};
    #pragma unroll 8
    for (int k = 0; k < 128; ++k) {
        float4 w = *(const float4*)&Wl[k][cq * 4];
        #pragma unroll
        for (int i = 0; i < 4; ++i) {
            float a = Al[rg * 4 + i][k];
            acc[i][0] = fmaf(a, w.x, acc[i][0]);
            acc[i][1] = fmaf(a, w.y, acc[i][1]);
            acc[i][2] = fmaf(a, w.z, acc[i][2]);
            acc[i][3] = fmaf(a, w.w, acc[i][3]);
        }
    }

    #pragma unroll
    for (int i = 0; i < 4; ++i) {
        size_t r = row0 + rg * 4 + i;
        float4 b = *(const float4*)(bias + cq * 4);
        float4 o = make_float4(acc[i][0] + b.x, acc[i][1] + b.y,
                               acc[i][2] + b.z, acc[i][3] + b.w);
        *(float4*)(out + r * DD + cq * 4) = o;
        bfu q0 = f2bf(o.x), q1 = f2bf(o.y), q2 = f2bf(o.z), q3 = f2bf(o.w);
        *(uint2*)(out16 + r * DD + cq * 4) =
            make_uint2((unsigned)q0 | ((unsigned)q1 << 16), (unsigned)q2 | ((unsigned)q3 << 16));
        *(unsigned*)(out8 + r * DD + cq * 4) = pk8(o.x, o.y, o.z, o.w);
    }
}

// ---------------- launch ----------------

extern "C" void kernel_launch(void* const* d_in, const int* in_sizes, int n_in,
                              void* d_out, int out_size, void* d_ws, size_t ws_size,
                              hipStream_t stream) {
    const float* x      = (const float*)d_in[0];
    const int*   eidx   = (const int*)d_in[1];
    const float* emb_w  = (const float*)d_in[3];
    const float* emb_b  = (const float*)d_in[4];
    const float* conv_ws = (const float*)d_in[5];
    const float* conv_b = (const float*)d_in[6];
    const float* ro_w   = (const float*)d_in[7];
    const float* ro_b   = (const float*)d_in[8];

    const int* src = eidx;
    const int* dst = eidx + EE;

    float* y  = (float*)d_out;                   // [N,128] final output
    float* hm = y + (size_t)NN * DD;             // [N,128] h_middle output

    // bufA lives in the y region (y is only written at the very end)
    bfu* bufA16          = (bfu*)y;
    unsigned char* bufA8 = (unsigned char*)(bufA16 + (size_t)NN * DD);  // 38.4 MB < 51.2 MB

    char* p = (char*)d_ws;
    const size_t FB  = (size_t)NN * DD * sizeof(float);
    const size_t FB2 = (size_t)NN * DD * sizeof(bfu);
    const size_t FB1 = (size_t)NN * DD;
    float* h     = (float*)p;           p += FB;
    bfu* h16     = (bfu*)p;             p += FB2;
    unsigned char* h8 = (unsigned char*)p;  p += FB1;
    bfu* hm16    = (bfu*)p;             p += FB2;
    unsigned char* hm8 = (unsigned char*)p; p += FB1;
    bfu* bufB16  = (bfu*)p;             p += FB2;
    float* dinv  = (float*)p;           p += (size_t)NN * 4;
    int* ideg    = (int*)p;             p += (size_t)NN * 4;
    int* row_ptr = (int*)p;             p += (size_t)(NN + 1) * 4;
    int* cursor  = (int*)p;             p += (size_t)NN * 4;
    int* partials = (int*)p;            p += (size_t)512 * 4;
    bfu* Wf      = (bfu*)p;             p += (size_t)4 * 16384 * sizeof(bfu);
    unsigned* cvp = (unsigned*)p;       p += (size_t)EE * 4;

    const int NB = (NN + 255) / 256;   // 391

    hipMemsetAsync(ideg, 0, (size_t)NN * 4, stream);
    count_deg_kernel<<<EE / 256, 256, 0, stream>>>(dst, ideg, EE);
    dinv_kernel<<<NB, 256, 0, stream>>>(ideg, dinv, NN);
    partial_sum_kernel<<<NB, 256, 0, stream>>>(ideg, partials, NN);
    scan_partials_kernel<<<1, 512, 0, stream>>>(partials, row_ptr, NB, NN);
    scan_block_kernel<<<NB, 256, 0, stream>>>(ideg, partials, row_ptr, cursor, NN);
    fill_csr_kernel<<<EE / 256, 256, 0, stream>>>(src, dst, dinv, cursor, cvp, EE);
    wfrag_kernel<<<4, 256, 0, stream>>>(conv_ws, ro_w, Wf);

    const int MM_GRID   = (NN + 63) / 64;     // 1563
    const int PROP_GRID = NN * 64 / 256;      // 25000

    // h = x @ emb_w + emb_b  (f32 master + bf16 + fp8)
    matmul_f32_kernel<<<NN / 32, 256, 0, stream>>>(x, emb_w, emb_b, h, h16, h8);

    for (int t = 0; t < 4; ++t) {
        // hm = h + 0.05*tanh(h@W0 + (Ph)@W1 + (P2h)@W2 + b)
        prop_kernel<true ><<<PROP_GRID, 256, 0, stream>>>(h8, bufA16, bufA8, row_ptr, cvp, NN);
        prop_kernel<false><<<PROP_GRID, 256, 0, stream>>>(bufA8, bufB16, nullptr, row_ptr, cvp, NN);
        mfma_mm_kernel<3, true><<<MM_GRID, 256, 0, stream>>>(
            h16, bufA16, bufB16, Wf, conv_b, h,
            (t == 3) ? hm : nullptr, hm16, hm8, 0.5f * EPSc);

        // h = h + 0.1*tanh(hm@W0 + (Phm)@W1 + (P2hm)@W2 + b)
        prop_kernel<true ><<<PROP_GRID, 256, 0, stream>>>(hm8, bufA16, bufA8, row_ptr, cvp, NN);
        prop_kernel<false><<<PROP_GRID, 256, 0, stream>>>(bufA8, bufB16, nullptr, row_ptr, cvp, NN);
        mfma_mm_kernel<3, true><<<MM_GRID, 256, 0, stream>>>(
            hm16, bufA16, bufB16, Wf, conv_b, h, h, h16, h8, EPSc);
    }

    // y = h_middle @ ro_w + ro_b   (overwrites the bufA scratch region)
    mfma_mm_kernel<1, false><<<MM_GRID, 256, 0, stream>>>(
        hm16, nullptr, nullptr, Wf + 3 * 16384, ro_b, nullptr, y, nullptr, nullptr, 0.f);
}

// Round 5
// 1484.806 us; speedup vs baseline: 2.9981x; 1.1196x over previous
//
#include <hip/hip_runtime.h>
#include <hip/hip_bf16.h>

#define NN 100000
#define EE 1600000
#define DD 128
#define EPSc 0.1f

typedef unsigned short bfu;
typedef __attribute__((ext_vector_type(8))) short short8;   // 8 bf16 = 4 VGPRs
typedef __attribute__((ext_vector_type(4))) float f32x4;
typedef __attribute__((ext_vector_type(2))) float f32x2;

__device__ __forceinline__ bfu f2bf(float f) {
    union { float f; unsigned u; } c; c.f = f;
    unsigned u = c.u + 0x7fffu + ((c.u >> 16) & 1u);   // RNE
    return (bfu)(u >> 16);
}
// pack 4 f32 -> 4 fp8 (OCP e4m3) bytes in one dword
__device__ __forceinline__ unsigned pk8(float a, float b, float c, float d) {
    int r = 0;
    r = __builtin_amdgcn_cvt_pk_fp8_f32(a, b, r, false);
    r = __builtin_amdgcn_cvt_pk_fp8_f32(c, d, r, true);
    return (unsigned)r;
}
__device__ __forceinline__ unsigned char enc8(float a) {
    return (unsigned char)(__builtin_amdgcn_cvt_pk_fp8_f32(a, a, 0, false) & 0xFF);
}
// expand 8 fp8 bytes -> short8 of bf16 (exact: e4m3 values are bf16-representable)
__device__ __forceinline__ short8 e8bf(uint2 u) {
    f32x2 p0 = __builtin_amdgcn_cvt_pk_f32_fp8((int)u.x, false);
    f32x2 p1 = __builtin_amdgcn_cvt_pk_f32_fp8((int)u.x, true);
    f32x2 p2 = __builtin_amdgcn_cvt_pk_f32_fp8((int)u.y, false);
    f32x2 p3 = __builtin_amdgcn_cvt_pk_f32_fp8((int)u.y, true);
    short8 s;
    s[0] = (short)f2bf(p0[0]); s[1] = (short)f2bf(p0[1]);
    s[2] = (short)f2bf(p1[0]); s[3] = (short)f2bf(p1[1]);
    s[4] = (short)f2bf(p2[0]); s[5] = (short)f2bf(p2[1]);
    s[6] = (short)f2bf(p3[0]); s[7] = (short)f2bf(p3[1]);
    return s;
}

// ---------------- CSR build ----------------

__global__ __launch_bounds__(256) void count_deg_kernel(const int* __restrict__ dst,
                                                        int* __restrict__ ideg, int e_cnt) {
    int e = blockIdx.x * 256 + threadIdx.x;
    if (e < e_cnt) atomicAdd(&ideg[dst[e]], 1);
}

__global__ __launch_bounds__(256) void dinv_kernel(const int* __restrict__ ideg,
                                                   float* __restrict__ dinv, int n) {
    int i = blockIdx.x * 256 + threadIdx.x;
    if (i < n) {
        int d = ideg[i];
        dinv[i] = (d > 0) ? rsqrtf((float)d) : 0.0f;
    }
}

__global__ __launch_bounds__(256) void partial_sum_kernel(const int* __restrict__ ideg,
                                                          int* __restrict__ partials, int n) {
    __shared__ int sm[256];
    int i = blockIdx.x * 256 + threadIdx.x;
    sm[threadIdx.x] = (i < n) ? ideg[i] : 0;
    __syncthreads();
    for (int off = 128; off > 0; off >>= 1) {
        if ((int)threadIdx.x < off) sm[threadIdx.x] += sm[threadIdx.x + off];
        __syncthreads();
    }
    if (threadIdx.x == 0) partials[blockIdx.x] = sm[0];
}

__global__ __launch_bounds__(512) void scan_partials_kernel(int* __restrict__ partials,
                                                            int* __restrict__ row_ptr,
                                                            int nb, int n) {
    __shared__ int sm[512];
    int v = ((int)threadIdx.x < nb) ? partials[threadIdx.x] : 0;
    sm[threadIdx.x] = v;
    __syncthreads();
    for (int off = 1; off < 512; off <<= 1) {
        int t = (threadIdx.x >= (unsigned)off) ? sm[threadIdx.x - off] : 0;
        __syncthreads();
        sm[threadIdx.x] += t;
        __syncthreads();
    }
    if ((int)threadIdx.x < nb) partials[threadIdx.x] = sm[threadIdx.x] - v;
    if (threadIdx.x == 511) row_ptr[n] = sm[511];
}

__global__ __launch_bounds__(256) void scan_block_kernel(const int* __restrict__ ideg,
                                                         const int* __restrict__ partials,
                                                         int* __restrict__ row_ptr,
                                                         int* __restrict__ cursor, int n) {
    __shared__ int sm[256];
    int i = blockIdx.x * 256 + threadIdx.x;
    int v = (i < n) ? ideg[i] : 0;
    sm[threadIdx.x] = v;
    __syncthreads();
    for (int off = 1; off < 256; off <<= 1) {
        int t = (threadIdx.x >= (unsigned)off) ? sm[threadIdx.x - off] : 0;
        __syncthreads();
        sm[threadIdx.x] += t;
        __syncthreads();
    }
    if (i < n) {
        int excl = partials[blockIdx.x] + sm[threadIdx.x] - v;
        row_ptr[i] = excl;
        cursor[i] = excl;
    }
}

// packed edge: top 15 bits = f32 val bits[31:17] (sign 0), low 17 bits = col
__global__ __launch_bounds__(256) void fill_csr_kernel(const int* __restrict__ src,
                                                       const int* __restrict__ dst,
                                                       const float* __restrict__ dinv,
                                                       int* __restrict__ cursor,
                                                       unsigned* __restrict__ cvp, int e_cnt) {
    int e = blockIdx.x * 256 + threadIdx.x;
    if (e < e_cnt) {
        int d = dst[e], s = src[e];
        int pos = atomicAdd(&cursor[d], 1);
        unsigned vb = __float_as_uint(dinv[s] * dinv[d]);
        unsigned r = vb + 0xFFFFu + ((vb >> 17) & 1u);   // RNE to 15-bit float
        cvp[pos] = (r & 0xFFFE0000u) | (unsigned)s;
    }
}

// ------------- weight -> bf16 MFMA-fragment-order transform -------------

__global__ __launch_bounds__(256) void wfrag_kernel(const float* __restrict__ conv_ws,
                                                    const float* __restrict__ ro_w,
                                                    bfu* __restrict__ Wf) {
    int m = blockIdx.x;   // 0..3
    const float* W = (m < 3) ? conv_ws + m * 16384 : ro_w;
    bfu* T = Wf + m * 16384;
    for (int j = 0; j < 64; ++j) {
        int i = threadIdx.x + j * 256;       // i = k*128 + n
        int k = i >> 7, n = i & 127;
        int nt = n >> 4, ks = k >> 5, kg = (k >> 3) & 3, jj = k & 7;
        int l = kg * 16 + (n & 15);
        int flat = ((nt * 4 + ks) * 64 + l) * 8 + jj;
        T[flat] = f2bf(W[i]);
    }
}

// ---------------- propagation (fp8 in / fp8 out, f32 accum) ----------------

__device__ __forceinline__ void acc8f8(uint2 u, float v, float* acc) {
    f32x2 p0 = __builtin_amdgcn_cvt_pk_f32_fp8((int)u.x, false);
    f32x2 p1 = __builtin_amdgcn_cvt_pk_f32_fp8((int)u.x, true);
    f32x2 p2 = __builtin_amdgcn_cvt_pk_f32_fp8((int)u.y, false);
    f32x2 p3 = __builtin_amdgcn_cvt_pk_f32_fp8((int)u.y, true);
    acc[0] = fmaf(v, p0[0], acc[0]); acc[1] = fmaf(v, p0[1], acc[1]);
    acc[2] = fmaf(v, p1[0], acc[2]); acc[3] = fmaf(v, p1[1], acc[3]);
    acc[4] = fmaf(v, p2[0], acc[4]); acc[5] = fmaf(v, p2[1], acc[5]);
    acc[6] = fmaf(v, p3[0], acc[6]); acc[7] = fmaf(v, p3[1], acc[7]);
}

__global__ __launch_bounds__(256) void prop_kernel(const unsigned char* __restrict__ xin8,
                                                   unsigned char* __restrict__ out8,
                                                   const int* __restrict__ row_ptr,
                                                   const unsigned* __restrict__ cvp, int n) {
    int wid = (blockIdx.x * 256 + threadIdx.x) >> 6;  // one wave per node
    int lane = threadIdx.x & 63;
    if (wid >= n) return;
    int s = row_ptr[wid];
    int e = row_ptr[wid + 1];
    int g = lane >> 4;        // edge slot 0..3
    int li = lane & 15;       // 16 lanes cover 128 dims (8 fp8 bytes each)
    float acc[8] = {0.f, 0.f, 0.f, 0.f, 0.f, 0.f, 0.f, 0.f};
    for (int ib = s; ib < e; ib += 16) {
        uint2 x[4];
        float v[4];
        #pragma unroll
        for (int q = 0; q < 4; ++q) {
            int i = ib + q * 4 + g;
            x[q] = make_uint2(0u, 0u);
            v[q] = 0.f;
            if (i < e) {
                unsigned c = cvp[i];
                v[q] = __uint_as_float(c & 0xFFFE0000u);
                x[q] = *(const uint2*)(xin8 + (size_t)(c & 0x1FFFFu) * DD + li * 8);
            }
        }
        #pragma unroll
        for (int q = 0; q < 4; ++q) acc8f8(x[q], v[q], acc);
    }
    #pragma unroll
    for (int k = 0; k < 8; ++k) {
        acc[k] += __shfl_xor(acc[k], 16);
        acc[k] += __shfl_xor(acc[k], 32);
    }
    if (g == 0) {
        uint2 q;
        q.x = pk8(acc[0], acc[1], acc[2], acc[3]);
        q.y = pk8(acc[4], acc[5], acc[6], acc[7]);
        *(uint2*)(out8 + (size_t)wid * DD + li * 8) = q;
    }
}

// ---------------- MFMA matmul: acc = sum_m A_m @ W_m, fused epilogue ----------------
// A8: A buffers are fp8 (expanded to bf16 in-register); else bf16.
// TANH: v = base + scale*tanh(acc+bias); outf?=v, out16?=bf16(v), out8=fp8(v)
// else: outf = acc + bias

template <int NMAT, bool TANH, bool A8>
__global__ __launch_bounds__(256) void mfma_mm_kernel(const void* __restrict__ A0,
                                                      const void* __restrict__ A1,
                                                      const void* __restrict__ A2,
                                                      const bfu* __restrict__ Wf,
                                                      const float* __restrict__ bias,
                                                      const float* __restrict__ base,
                                                      float* __restrict__ outf,
                                                      bfu* __restrict__ out16,
                                                      unsigned char* __restrict__ out8,
                                                      float scale) {
    int tid = threadIdx.x;
    int wave = tid >> 6, lane = tid & 63;
    int r0 = blockIdx.x * 64 + wave * 16;
    int li = lane & 15, kg = lane >> 4;
    int rowA = r0 + li;
    bool rv = rowA < NN;
    size_t arow = (size_t)(rv ? rowA : 0) * DD;   // elements

    const void* As[3] = {A0, A1, A2};
    short8 a[NMAT][4];
    #pragma unroll
    for (int m = 0; m < NMAT; ++m) {
        #pragma unroll
        for (int ks = 0; ks < 4; ++ks) {
            short8 t;
            if (A8) {
                uint2 u = *(const uint2*)((const unsigned char*)As[m] + arow + ks * 32 + kg * 8);
                t = e8bf(u);
            } else {
                t = *(const short8*)((const bfu*)As[m] + arow + ks * 32 + kg * 8);
            }
            if (!rv) t = (short8)0;
            a[m][ks] = t;
        }
    }

    const short8* Bp = (const short8*)Wf;   // [NMAT][32][64] short8
    f32x4 acc[8];
    #pragma unroll
    for (int nt = 0; nt < 8; ++nt) acc[nt] = (f32x4)(0.f);
    #pragma unroll
    for (int nt = 0; nt < 8; ++nt) {
        #pragma unroll
        for (int m = 0; m < NMAT; ++m) {
            #pragma unroll
            for (int ks = 0; ks < 4; ++ks) {
                short8 b = Bp[m * 2048 + (nt * 4 + ks) * 64 + lane];
                acc[nt] = __builtin_amdgcn_mfma_f32_16x16x32_bf16(a[m][ks], b, acc[nt], 0, 0, 0);
            }
        }
    }

    #pragma unroll
    for (int nt = 0; nt < 8; ++nt) {
        int cc = nt * 16 + li;
        float bv = bias[cc];
        #pragma unroll
        for (int rg = 0; rg < 4; ++rg) {
            int rr = r0 + kg * 4 + rg;
            if (rr < NN) {
                size_t off = (size_t)rr * DD + cc;
                float o = acc[nt][rg];
                if (TANH) {
                    float ov = base[off] + scale * tanhf(o + bv);
                    if (outf) outf[off] = ov;
                    if (out16) out16[off] = f2bf(ov);
                    out8[off] = enc8(ov);
                } else {
                    outf[off] = o + bv;
                }
            }
        }
    }
}

// ---------------- f32 matmul for embedding: h = x@W + b (+fp8 shadow) ----------------

__global__ __launch_bounds__(256) void matmul_f32_kernel(const float* __restrict__ A,
                                                         const float* __restrict__ W,
                                                         const float* __restrict__ bias,
                                                         float* __restrict__ out,
                                                         unsigned char* __restrict__ out8) {
    __shared__ float Wl[128][128];
    __shared__ float Al[32][128];
    int tid = threadIdx.x;

    const float4* Wv = (const float4*)W;
    float4* Wlv = (float4*)&Wl[0][0];
    #pragma unroll
    for (int i = 0; i < 16; ++i) Wlv[tid + i * 256] = Wv[tid + i * 256];

    size_t row0 = (size_t)blockIdx.x * 32;
    const float4* Av = (const float4*)(A + row0 * DD);
    float4* Alv = (float4*)&Al[0][0];
    #pragma unroll
    for (int i = 0; i < 4; ++i) Alv[tid + i * 256] = Av[tid + i * 256];
    __syncthreads();

    int cq = tid & 31;
    int rg = tid >> 5;
    float acc[4][4] = {};
    #pragma unroll 8
    for (int k = 0; k < 128; ++k) {
        float4 w = *(const float4*)&Wl[k][cq * 4];
        #pragma unroll
        for (int i = 0; i < 4; ++i) {
            float a = Al[rg * 4 + i][k];
            acc[i][0] = fmaf(a, w.x, acc[i][0]);
            acc[i][1] = fmaf(a, w.y, acc[i][1]);
            acc[i][2] = fmaf(a, w.z, acc[i][2]);
            acc[i][3] = fmaf(a, w.w, acc[i][3]);
        }
    }

    #pragma unroll
    for (int i = 0; i < 4; ++i) {
        size_t r = row0 + rg * 4 + i;
        float4 b = *(const float4*)(bias + cq * 4);
        float4 o = make_float4(acc[i][0] + b.x, acc[i][1] + b.y,
                               acc[i][2] + b.z, acc[i][3] + b.w);
        *(float4*)(out + r * DD + cq * 4) = o;
        *(unsigned*)(out8 + r * DD + cq * 4) = pk8(o.x, o.y, o.z, o.w);
    }
}

// ---------------- launch ----------------

extern "C" void kernel_launch(void* const* d_in, const int* in_sizes, int n_in,
                              void* d_out, int out_size, void* d_ws, size_t ws_size,
                              hipStream_t stream) {
    const float* x      = (const float*)d_in[0];
    const int*   eidx   = (const int*)d_in[1];
    const float* emb_w  = (const float*)d_in[3];
    const float* emb_b  = (const float*)d_in[4];
    const float* conv_ws = (const float*)d_in[5];
    const float* conv_b = (const float*)d_in[6];
    const float* ro_w   = (const float*)d_in[7];
    const float* ro_b   = (const float*)d_in[8];

    const int* src = eidx;
    const int* dst = eidx + EE;

    float* y  = (float*)d_out;                   // [N,128] final output
    float* hm = y + (size_t)NN * DD;             // [N,128] h_middle output

    char* p = (char*)d_ws;
    const size_t FB  = (size_t)NN * DD * sizeof(float);
    const size_t FB2 = (size_t)NN * DD * sizeof(bfu);
    const size_t FB1 = (size_t)NN * DD;
    float* h     = (float*)p;               p += FB;
    unsigned char* h8  = (unsigned char*)p; p += FB1;
    unsigned char* hm8 = (unsigned char*)p; p += FB1;
    unsigned char* bufA8 = (unsigned char*)p; p += FB1;
    unsigned char* bufB8 = (unsigned char*)p; p += FB1;
    bfu* hm16    = (bfu*)p;                 p += FB2;
    float* dinv  = (float*)p;               p += (size_t)NN * 4;
    int* ideg    = (int*)p;                 p += (size_t)NN * 4;
    int* row_ptr = (int*)p;                 p += (size_t)(NN + 1) * 4;
    int* cursor  = (int*)p;                 p += (size_t)NN * 4;
    int* partials = (int*)p;                p += (size_t)512 * 4;
    bfu* Wf      = (bfu*)p;                 p += (size_t)4 * 16384 * sizeof(bfu);
    unsigned* cvp = (unsigned*)p;           p += (size_t)EE * 4;

    const int NB = (NN + 255) / 256;   // 391

    hipMemsetAsync(ideg, 0, (size_t)NN * 4, stream);
    count_deg_kernel<<<EE / 256, 256, 0, stream>>>(dst, ideg, EE);
    dinv_kernel<<<NB, 256, 0, stream>>>(ideg, dinv, NN);
    partial_sum_kernel<<<NB, 256, 0, stream>>>(ideg, partials, NN);
    scan_partials_kernel<<<1, 512, 0, stream>>>(partials, row_ptr, NB, NN);
    scan_block_kernel<<<NB, 256, 0, stream>>>(ideg, partials, row_ptr, cursor, NN);
    fill_csr_kernel<<<EE / 256, 256, 0, stream>>>(src, dst, dinv, cursor, cvp, EE);
    wfrag_kernel<<<4, 256, 0, stream>>>(conv_ws, ro_w, Wf);

    const int MM_GRID   = (NN + 63) / 64;     // 1563
    const int PROP_GRID = NN * 64 / 256;      // 25000

    // h = x @ emb_w + emb_b  (f32 master + fp8 shadow)
    matmul_f32_kernel<<<NN / 32, 256, 0, stream>>>(x, emb_w, emb_b, h, h8);

    for (int t = 0; t < 4; ++t) {
        // hm = h + 0.05*tanh(h@W0 + (Ph)@W1 + (P2h)@W2 + b)
        prop_kernel<<<PROP_GRID, 256, 0, stream>>>(h8, bufA8, row_ptr, cvp, NN);
        prop_kernel<<<PROP_GRID, 256, 0, stream>>>(bufA8, bufB8, row_ptr, cvp, NN);
        mfma_mm_kernel<3, true, true><<<MM_GRID, 256, 0, stream>>>(
            h8, bufA8, bufB8, Wf, conv_b, h,
            (t == 3) ? hm : nullptr, (t == 3) ? hm16 : nullptr, hm8, 0.5f * EPSc);

        // h = h + 0.1*tanh(hm@W0 + (Phm)@W1 + (P2hm)@W2 + b)
        prop_kernel<<<PROP_GRID, 256, 0, stream>>>(hm8, bufA8, row_ptr, cvp, NN);
        prop_kernel<<<PROP_GRID, 256, 0, stream>>>(bufA8, bufB8, row_ptr, cvp, NN);
        mfma_mm_kernel<3, true, true><<<MM_GRID, 256, 0, stream>>>(
            hm8, bufA8, bufB8, Wf, conv_b, h, h, nullptr, h8, EPSc);
    }

    // y = h_middle @ ro_w + ro_b  (bf16 A-path for output accuracy)
    mfma_mm_kernel<1, false, false><<<MM_GRID, 256, 0, stream>>>(
        hm16, nullptr, nullptr, Wf + 3 * 16384, ro_b, nullptr, y, nullptr, nullptr, 0.f);
}

// Round 6
// 1284.089 us; speedup vs baseline: 3.4667x; 1.1563x over previous
//
#include <hip/hip_runtime.h>
#include <hip/hip_bf16.h>

#define NN 100000
#define EE 1600000
#define DD 128
#define EPSc 0.1f

typedef unsigned short bfu;
typedef __attribute__((ext_vector_type(8))) short short8;   // 8 bf16 = 4 VGPRs
typedef __attribute__((ext_vector_type(4))) float f32x4;
typedef __attribute__((ext_vector_type(2))) float f32x2;

__device__ __forceinline__ float bf2f(bfu s) {
    union { unsigned u; float f; } c; c.u = ((unsigned)s) << 16; return c.f;
}
__device__ __forceinline__ bfu f2bf(float f) {
    union { float f; unsigned u; } c; c.f = f;
    unsigned u = c.u + 0x7fffu + ((c.u >> 16) & 1u);   // RNE
    return (bfu)(u >> 16);
}
// pack 4 f32 -> 4 fp8 (OCP e4m3) bytes in one dword
__device__ __forceinline__ unsigned pk8(float a, float b, float c, float d) {
    int r = 0;
    r = __builtin_amdgcn_cvt_pk_fp8_f32(a, b, r, false);
    r = __builtin_amdgcn_cvt_pk_fp8_f32(c, d, r, true);
    return (unsigned)r;
}
__device__ __forceinline__ unsigned char enc8(float a) {
    return (unsigned char)(__builtin_amdgcn_cvt_pk_fp8_f32(a, a, 0, false) & 0xFF);
}
// expand 8 fp8 bytes -> short8 of bf16 (exact: e4m3 values are bf16-representable)
__device__ __forceinline__ short8 e8bf(uint2 u) {
    f32x2 p0 = __builtin_amdgcn_cvt_pk_f32_fp8((int)u.x, false);
    f32x2 p1 = __builtin_amdgcn_cvt_pk_f32_fp8((int)u.x, true);
    f32x2 p2 = __builtin_amdgcn_cvt_pk_f32_fp8((int)u.y, false);
    f32x2 p3 = __builtin_amdgcn_cvt_pk_f32_fp8((int)u.y, true);
    short8 s;
    s[0] = (short)f2bf(p0[0]); s[1] = (short)f2bf(p0[1]);
    s[2] = (short)f2bf(p1[0]); s[3] = (short)f2bf(p1[1]);
    s[4] = (short)f2bf(p2[0]); s[5] = (short)f2bf(p2[1]);
    s[6] = (short)f2bf(p3[0]); s[7] = (short)f2bf(p3[1]);
    return s;
}

// ---------------- CSR build ----------------

__global__ __launch_bounds__(256) void count_deg_kernel(const int* __restrict__ dst,
                                                        int* __restrict__ ideg, int e_cnt) {
    int e = blockIdx.x * 256 + threadIdx.x;
    if (e < e_cnt) atomicAdd(&ideg[dst[e]], 1);
}

__global__ __launch_bounds__(256) void dinv_kernel(const int* __restrict__ ideg,
                                                   float* __restrict__ dinv, int n) {
    int i = blockIdx.x * 256 + threadIdx.x;
    if (i < n) {
        int d = ideg[i];
        dinv[i] = (d > 0) ? rsqrtf((float)d) : 0.0f;
    }
}

__global__ __launch_bounds__(256) void partial_sum_kernel(const int* __restrict__ ideg,
                                                          int* __restrict__ partials, int n) {
    __shared__ int sm[256];
    int i = blockIdx.x * 256 + threadIdx.x;
    sm[threadIdx.x] = (i < n) ? ideg[i] : 0;
    __syncthreads();
    for (int off = 128; off > 0; off >>= 1) {
        if ((int)threadIdx.x < off) sm[threadIdx.x] += sm[threadIdx.x + off];
        __syncthreads();
    }
    if (threadIdx.x == 0) partials[blockIdx.x] = sm[0];
}

__global__ __launch_bounds__(512) void scan_partials_kernel(int* __restrict__ partials,
                                                            int* __restrict__ row_ptr,
                                                            int nb, int n) {
    __shared__ int sm[512];
    int v = ((int)threadIdx.x < nb) ? partials[threadIdx.x] : 0;
    sm[threadIdx.x] = v;
    __syncthreads();
    for (int off = 1; off < 512; off <<= 1) {
        int t = (threadIdx.x >= (unsigned)off) ? sm[threadIdx.x - off] : 0;
        __syncthreads();
        sm[threadIdx.x] += t;
        __syncthreads();
    }
    if ((int)threadIdx.x < nb) partials[threadIdx.x] = sm[threadIdx.x] - v;
    if (threadIdx.x == 511) row_ptr[n] = sm[511];
}

__global__ __launch_bounds__(256) void scan_block_kernel(const int* __restrict__ ideg,
                                                         const int* __restrict__ partials,
                                                         int* __restrict__ row_ptr,
                                                         int* __restrict__ cursor, int n) {
    __shared__ int sm[256];
    int i = blockIdx.x * 256 + threadIdx.x;
    int v = (i < n) ? ideg[i] : 0;
    sm[threadIdx.x] = v;
    __syncthreads();
    for (int off = 1; off < 256; off <<= 1) {
        int t = (threadIdx.x >= (unsigned)off) ? sm[threadIdx.x - off] : 0;
        __syncthreads();
        sm[threadIdx.x] += t;
        __syncthreads();
    }
    if (i < n) {
        int excl = partials[blockIdx.x] + sm[threadIdx.x] - v;
        row_ptr[i] = excl;
        cursor[i] = excl;
    }
}

// packed edge: top 15 bits = f32 val bits[31:17] (sign 0), low 17 bits = col
__global__ __launch_bounds__(256) void fill_csr_kernel(const int* __restrict__ src,
                                                       const int* __restrict__ dst,
                                                       const float* __restrict__ dinv,
                                                       int* __restrict__ cursor,
                                                       unsigned* __restrict__ cvp, int e_cnt) {
    int e = blockIdx.x * 256 + threadIdx.x;
    if (e < e_cnt) {
        int d = dst[e], s = src[e];
        int pos = atomicAdd(&cursor[d], 1);
        unsigned vb = __float_as_uint(dinv[s] * dinv[d]);
        unsigned r = vb + 0xFFFFu + ((vb >> 17) & 1u);   // RNE to 15-bit float
        cvp[pos] = (r & 0xFFFE0000u) | (unsigned)s;
    }
}

// ------------- weight -> bf16 MFMA-fragment-order transform -------------

__global__ __launch_bounds__(256) void wfrag_kernel(const float* __restrict__ conv_ws,
                                                    const float* __restrict__ ro_w,
                                                    bfu* __restrict__ Wf) {
    int m = blockIdx.x;   // 0..3
    const float* W = (m < 3) ? conv_ws + m * 16384 : ro_w;
    bfu* T = Wf + m * 16384;
    for (int j = 0; j < 64; ++j) {
        int i = threadIdx.x + j * 256;       // i = k*128 + n
        int k = i >> 7, n = i & 127;
        int nt = n >> 4, ks = k >> 5, kg = (k >> 3) & 3, jj = k & 7;
        int l = kg * 16 + (n & 15);
        int flat = ((nt * 4 + ks) * 64 + l) * 8 + jj;
        T[flat] = f2bf(W[i]);
    }
}

// ---------------- propagation (fp8 in / fp8 out, f32 accum) ----------------
// Edge words fetched once per wave (coalesced), broadcast via shfl -> gather
// addresses have no dependent-load latency; 16 row-gathers in flight.

__device__ __forceinline__ void acc8f8(uint2 u, float v, float* acc) {
    f32x2 p0 = __builtin_amdgcn_cvt_pk_f32_fp8((int)u.x, false);
    f32x2 p1 = __builtin_amdgcn_cvt_pk_f32_fp8((int)u.x, true);
    f32x2 p2 = __builtin_amdgcn_cvt_pk_f32_fp8((int)u.y, false);
    f32x2 p3 = __builtin_amdgcn_cvt_pk_f32_fp8((int)u.y, true);
    acc[0] = fmaf(v, p0[0], acc[0]); acc[1] = fmaf(v, p0[1], acc[1]);
    acc[2] = fmaf(v, p1[0], acc[2]); acc[3] = fmaf(v, p1[1], acc[3]);
    acc[4] = fmaf(v, p2[0], acc[4]); acc[5] = fmaf(v, p2[1], acc[5]);
    acc[6] = fmaf(v, p3[0], acc[6]); acc[7] = fmaf(v, p3[1], acc[7]);
}

__global__ __launch_bounds__(256) void prop_kernel(const unsigned char* __restrict__ xin8,
                                                   unsigned char* __restrict__ out8,
                                                   const int* __restrict__ row_ptr,
                                                   const unsigned* __restrict__ cvp, int n) {
    int wid = (blockIdx.x * 256 + threadIdx.x) >> 6;  // one wave per node
    int lane = threadIdx.x & 63;
    if (wid >= n) return;
    int s = row_ptr[wid];
    int deg = row_ptr[wid + 1] - s;
    int g = lane >> 4;        // edge slot group 0..3
    int li = lane & 15;       // 16 lanes cover 128 dims (8 fp8 bytes each)
    float acc[8] = {0.f, 0.f, 0.f, 0.f, 0.f, 0.f, 0.f, 0.f};
    for (int base = 0; base < deg; base += 64) {
        int cnt = deg - base; if (cnt > 64) cnt = 64;
        unsigned el = (lane < cnt) ? cvp[s + base + lane] : 0u;   // coalesced
        for (int q = 0; q < cnt; q += 16) {
            uint2 x[4]; float v[4];
            #pragma unroll
            for (int j = 0; j < 4; ++j) {
                int idx = q + j * 4 + g;
                unsigned c = __shfl(el, idx);
                bool valid = idx < cnt;
                v[j] = valid ? __uint_as_float(c & 0xFFFE0000u) : 0.f;
                x[j] = valid ? *(const uint2*)(xin8 + (size_t)(c & 0x1FFFFu) * DD + li * 8)
                             : make_uint2(0u, 0u);
            }
            #pragma unroll
            for (int j = 0; j < 4; ++j) acc8f8(x[j], v[j], acc);
        }
    }
    #pragma unroll
    for (int k = 0; k < 8; ++k) {
        acc[k] += __shfl_xor(acc[k], 16);
        acc[k] += __shfl_xor(acc[k], 32);
    }
    if (g == 0) {
        uint2 q;
        q.x = pk8(acc[0], acc[1], acc[2], acc[3]);
        q.y = pk8(acc[4], acc[5], acc[6], acc[7]);
        *(uint2*)(out8 + (size_t)wid * DD + li * 8) = q;
    }
}

// ---------------- MFMA matmul: acc = sum_m A_m @ W_m, fused epilogue ----------------
// A8: A buffers fp8 (expanded to bf16 in-register); else bf16.
// TANH: v = bf2f(base16) + scale*tanh(acc+bias); outf?=v, out16?=bf16(v), out8=fp8(v)
// else: outf = acc + bias

template <int NMAT, bool TANH, bool A8>
__global__ __launch_bounds__(256) void mfma_mm_kernel(const void* __restrict__ A0,
                                                      const void* __restrict__ A1,
                                                      const void* __restrict__ A2,
                                                      const bfu* __restrict__ Wf,
                                                      const float* __restrict__ bias,
                                                      const bfu* __restrict__ base16,
                                                      float* __restrict__ outf,
                                                      bfu* __restrict__ out16,
                                                      unsigned char* __restrict__ out8,
                                                      float scale) {
    int tid = threadIdx.x;
    int wave = tid >> 6, lane = tid & 63;
    int r0 = blockIdx.x * 64 + wave * 16;
    int li = lane & 15, kg = lane >> 4;
    int rowA = r0 + li;
    bool rv = rowA < NN;
    size_t arow = (size_t)(rv ? rowA : 0) * DD;   // elements

    const void* As[3] = {A0, A1, A2};
    short8 a[NMAT][4];
    #pragma unroll
    for (int m = 0; m < NMAT; ++m) {
        #pragma unroll
        for (int ks = 0; ks < 4; ++ks) {
            short8 t;
            if (A8) {
                uint2 u = *(const uint2*)((const unsigned char*)As[m] + arow + ks * 32 + kg * 8);
                t = e8bf(u);
            } else {
                t = *(const short8*)((const bfu*)As[m] + arow + ks * 32 + kg * 8);
            }
            if (!rv) t = (short8)0;
            a[m][ks] = t;
        }
    }

    const short8* Bp = (const short8*)Wf;   // [NMAT][32][64] short8
    f32x4 acc[8];
    #pragma unroll
    for (int nt = 0; nt < 8; ++nt) acc[nt] = (f32x4)(0.f);
    #pragma unroll
    for (int nt = 0; nt < 8; ++nt) {
        #pragma unroll
        for (int m = 0; m < NMAT; ++m) {
            #pragma unroll
            for (int ks = 0; ks < 4; ++ks) {
                short8 b = Bp[m * 2048 + (nt * 4 + ks) * 64 + lane];
                acc[nt] = __builtin_amdgcn_mfma_f32_16x16x32_bf16(a[m][ks], b, acc[nt], 0, 0, 0);
            }
        }
    }

    #pragma unroll
    for (int nt = 0; nt < 8; ++nt) {
        int cc = nt * 16 + li;
        float bv = bias[cc];
        #pragma unroll
        for (int rg = 0; rg < 4; ++rg) {
            int rr = r0 + kg * 4 + rg;
            if (rr < NN) {
                size_t off = (size_t)rr * DD + cc;
                float o = acc[nt][rg];
                if (TANH) {
                    float ov = bf2f(base16[off]) + scale * tanhf(o + bv);
                    if (outf) outf[off] = ov;
                    if (out16) out16[off] = f2bf(ov);
                    out8[off] = enc8(ov);
                } else {
                    outf[off] = o + bv;
                }
            }
        }
    }
}

// ---------------- f32 matmul for embedding: h = x@W + b -> bf16 + fp8 ----------------

__global__ __launch_bounds__(256) void matmul_f32_kernel(const float* __restrict__ A,
                                                         const float* __restrict__ W,
                                                         const float* __restrict__ bias,
                                                         bfu* __restrict__ out16,
                                                         unsigned char* __restrict__ out8) {
    __shared__ float Wl[128][128];
    __shared__ float Al[32][128];
    int tid = threadIdx.x;

    const float4* Wv = (const float4*)W;
    float4* Wlv = (float4*)&Wl[0][0];
    #pragma unroll
    for (int i = 0; i < 16; ++i) Wlv[tid + i * 256] = Wv[tid + i * 256];

    size_t row0 = (size_t)blockIdx.x * 32;
    const float4* Av = (const float4*)(A + row0 * DD);
    float4* Alv = (float4*)&Al[0][0];
    #pragma unroll
    for (int i = 0; i < 4; ++i) Alv[tid + i * 256] = Av[tid + i * 256];
    __syncthreads();

    int cq = tid & 31;
    int rg = tid >> 5;
    float acc[4][4] = {};
    #pragma unroll 8
    for (int k = 0; k < 128; ++k) {
        float4 w = *(const float4*)&Wl[k][cq * 4];
        #pragma unroll
        for (int i = 0; i < 4; ++i) {
            float a = Al[rg * 4 + i][k];
            acc[i][0] = fmaf(a, w.x, acc[i][0]);
            acc[i][1] = fmaf(a, w.y, acc[i][1]);
            acc[i][2] = fmaf(a, w.z, acc[i][2]);
            acc[i][3] = fmaf(a, w.w, acc[i][3]);
        }
    }

    #pragma unroll
    for (int i = 0; i < 4; ++i) {
        size_t r = row0 + rg * 4 + i;
        float4 b = *(const float4*)(bias + cq * 4);
        float4 o = make_float4(acc[i][0] + b.x, acc[i][1] + b.y,
                               acc[i][2] + b.z, acc[i][3] + b.w);
        bfu q0 = f2bf(o.x), q1 = f2bf(o.y), q2 = f2bf(o.z), q3 = f2bf(o.w);
        *(uint2*)(out16 + r * DD + cq * 4) =
            make_uint2((unsigned)q0 | ((unsigned)q1 << 16), (unsigned)q2 | ((unsigned)q3 << 16));
        *(unsigned*)(out8 + r * DD + cq * 4) = pk8(o.x, o.y, o.z, o.w);
    }
}

// ---------------- launch ----------------

extern "C" void kernel_launch(void* const* d_in, const int* in_sizes, int n_in,
                              void* d_out, int out_size, void* d_ws, size_t ws_size,
                              hipStream_t stream) {
    const float* x      = (const float*)d_in[0];
    const int*   eidx   = (const int*)d_in[1];
    const float* emb_w  = (const float*)d_in[3];
    const float* emb_b  = (const float*)d_in[4];
    const float* conv_ws = (const float*)d_in[5];
    const float* conv_b = (const float*)d_in[6];
    const float* ro_w   = (const float*)d_in[7];
    const float* ro_b   = (const float*)d_in[8];

    const int* src = eidx;
    const int* dst = eidx + EE;

    float* y  = (float*)d_out;                   // [N,128] final output
    float* hm = y + (size_t)NN * DD;             // [N,128] h_middle f32 output

    char* p = (char*)d_ws;
    const size_t FB2 = (size_t)NN * DD * sizeof(bfu);   // 25.6 MB
    const size_t FB1 = (size_t)NN * DD;                 // 12.8 MB
    bfu* h16     = (bfu*)p;                 p += FB2;   // bf16 master state
    bfu* hm16    = (bfu*)p;                 p += FB2;   // bf16 h_middle (t==3 only)
    unsigned char* h8  = (unsigned char*)p; p += FB1;
    unsigned char* hm8 = (unsigned char*)p; p += FB1;
    unsigned char* bufA8 = (unsigned char*)p; p += FB1;
    unsigned char* bufB8 = (unsigned char*)p; p += FB1;
    float* dinv  = (float*)p;               p += (size_t)NN * 4;
    int* ideg    = (int*)p;                 p += (size_t)NN * 4;
    int* row_ptr = (int*)p;                 p += (size_t)(NN + 1) * 4;
    int* cursor  = (int*)p;                 p += (size_t)NN * 4;
    int* partials = (int*)p;                p += (size_t)512 * 4;
    bfu* Wf      = (bfu*)p;                 p += (size_t)4 * 16384 * sizeof(bfu);
    unsigned* cvp = (unsigned*)p;           p += (size_t)EE * 4;

    const int NB = (NN + 255) / 256;   // 391

    hipMemsetAsync(ideg, 0, (size_t)NN * 4, stream);
    count_deg_kernel<<<EE / 256, 256, 0, stream>>>(dst, ideg, EE);
    dinv_kernel<<<NB, 256, 0, stream>>>(ideg, dinv, NN);
    partial_sum_kernel<<<NB, 256, 0, stream>>>(ideg, partials, NN);
    scan_partials_kernel<<<1, 512, 0, stream>>>(partials, row_ptr, NB, NN);
    scan_block_kernel<<<NB, 256, 0, stream>>>(ideg, partials, row_ptr, cursor, NN);
    fill_csr_kernel<<<EE / 256, 256, 0, stream>>>(src, dst, dinv, cursor, cvp, EE);
    wfrag_kernel<<<4, 256, 0, stream>>>(conv_ws, ro_w, Wf);

    const int MM_GRID   = (NN + 63) / 64;     // 1563
    const int PROP_GRID = NN * 64 / 256;      // 25000

    // h = x @ emb_w + emb_b  (bf16 master + fp8 shadow; no f32 state)
    matmul_f32_kernel<<<NN / 32, 256, 0, stream>>>(x, emb_w, emb_b, h16, h8);

    for (int t = 0; t < 4; ++t) {
        // hm = h + 0.05*tanh(h@W0 + (Ph)@W1 + (P2h)@W2 + b)
        prop_kernel<<<PROP_GRID, 256, 0, stream>>>(h8, bufA8, row_ptr, cvp, NN);
        prop_kernel<<<PROP_GRID, 256, 0, stream>>>(bufA8, bufB8, row_ptr, cvp, NN);
        mfma_mm_kernel<3, true, true><<<MM_GRID, 256, 0, stream>>>(
            h8, bufA8, bufB8, Wf, conv_b, h16,
            (t == 3) ? hm : nullptr, (t == 3) ? hm16 : nullptr, hm8, 0.5f * EPSc);

        // h = h + 0.1*tanh(hm@W0 + (Phm)@W1 + (P2hm)@W2 + b)
        prop_kernel<<<PROP_GRID, 256, 0, stream>>>(hm8, bufA8, row_ptr, cvp, NN);
        prop_kernel<<<PROP_GRID, 256, 0, stream>>>(bufA8, bufB8, row_ptr, cvp, NN);
        mfma_mm_kernel<3, true, true><<<MM_GRID, 256, 0, stream>>>(
            hm8, bufA8, bufB8, Wf, conv_b, h16, nullptr, h16, h8, EPSc);
    }

    // y = h_middle @ ro_w + ro_b  (bf16 A-path for output accuracy)
    mfma_mm_kernel<1, false, false><<<MM_GRID, 256, 0, stream>>>(
        hm16, nullptr, nullptr, Wf + 3 * 16384, ro_b, nullptr, y, nullptr, nullptr, 0.f);
}